// Round 2
// baseline (15923.843 us; speedup 1.0000x reference)
//
#include <hip/hip_runtime.h>
#include <hip/hip_bf16.h>
#include <math.h>

typedef _Float16 f16x8 __attribute__((ext_vector_type(8)));
typedef float    f32x4 __attribute__((ext_vector_type(4)));

#define DEV __device__ __forceinline__

static constexpr int Ee   = 300;   // glove dim
static constexpr int INP  = 303;   // E + 3
static constexpr int INPP = 320;   // padded input dim
static constexpr int Hh   = 512;
static constexpr int Bb   = 64;
static constexpr int Tt   = 512;
static constexpr int D2H  = 1024;  // 2H

// ---- MFMA fragment load: K-major matrix M[row][k], frag[l][j] = M[row0+(l&15)][k0+8*(l>>4)+j]
DEV f16x8 ldfrag(const _Float16* base, int ld, int row0, int k0, int lane) {
  return *reinterpret_cast<const f16x8*>(base + (size_t)(row0 + (lane & 15)) * ld + (k0 + 8 * (lane >> 4)));
}
DEV float sigm(float x) { return 1.0f / (1.0f + expf(-x)); }

// ---------------- weight convert (f32 -> f16, optional column pad) ----------------
__global__ void convert_pad(const float* __restrict__ src, _Float16* __restrict__ dst,
                            int rows, int csrc, int cdst) {
  int i = blockIdx.x * 256 + threadIdx.x;
  if (i >= rows * cdst) return;
  int r = i / cdst, c = i - r * cdst;
  dst[i] = (c < csrc) ? (_Float16)src[(size_t)r * csrc + c] : (_Float16)0.0f;
}

// ---------------- embedding: xt (T, B, INPP) f16 ----------------
__global__ void embed_kernel(const int* __restrict__ context, const int* __restrict__ tags,
                             const float* __restrict__ glove, const float* __restrict__ bio,
                             _Float16* __restrict__ xt) {
  int blk = blockIdx.x;            // t*64 + b
  int t = blk >> 6, b = blk & 63;
  int cid = context[b * Tt + t];   // context (B,T,1)
  int tag = tags[b * Tt + t];      // (B,T)
  _Float16* dst = xt + (size_t)blk * INPP;
  for (int c = threadIdx.x; c < INPP; c += 64) {
    float v = (c < Ee) ? glove[(size_t)cid * Ee + c]
                       : ((c < INP) ? bio[tag * 3 + (c - Ee)] : 0.0f);
    dst[c] = (_Float16)v;
  }
}

// ---------------- persistent GRU recurrence ----------------
struct GruParams {
  const _Float16* xt;
  const _Float16* Wx[2][2];   // [dir][layer] input-side weights (ld = 320 or 512)
  const _Float16* Wh[2][2];   // hidden-side weights (ld = 512)
  const float* bih[2][2];
  const float* bhh[2][2];
  float*     h32[2][2];       // 2 slots x 64 x 512 each
  _Float16*  h16[2][2];
  _Float16*  allh;            // (B, T, 2H) f16
};

// device-scope grid barrier over one direction group (64 blocks)
DEV void gridbar(unsigned* ctr, unsigned tgt) {
  __syncthreads();                 // emits vmcnt(0) drain: all this block's stores visible at L2
  if (threadIdx.x == 0) {
    __threadfence();               // agent-scope: write back local L2 (cross-XCD visibility)
    __hip_atomic_fetch_add(ctr, 1u, __ATOMIC_RELEASE, __HIP_MEMORY_SCOPE_AGENT);
    while (__hip_atomic_load(ctr, __ATOMIC_RELAXED, __HIP_MEMORY_SCOPE_AGENT) < tgt)
      __builtin_amdgcn_s_sleep(1);
    __threadfence();               // agent-scope acquire: invalidate stale L1/L2 lines
  }
  __syncthreads();
}

// acc += A(64xKX, ld=LDA) * B(rows nrow.., ld=LDB)^T
template<int KX, int LDA, int LDB>
DEV void mmacc(f32x4* acc, const _Float16* __restrict__ A,
               const _Float16* __restrict__ Bm, int nrow, int lane) {
  const _Float16* arow = A + (size_t)(lane & 15) * LDA + 8 * (lane >> 4);
  const _Float16* brow = Bm + (size_t)(nrow + (lane & 15)) * LDB + 8 * (lane >> 4);
#pragma unroll 4
  for (int k0 = 0; k0 < KX; k0 += 32) {
    f16x8 bfr = *(const f16x8*)(brow + k0);
#pragma unroll
    for (int mt = 0; mt < 4; ++mt) {
      f16x8 afr = *(const f16x8*)(arow + (size_t)mt * 16 * LDA + k0);
      acc[mt] = __builtin_amdgcn_mfma_f32_16x16x32_f16(afr, bfr, acc[mt], 0, 0, 0);
    }
  }
}

__global__ __launch_bounds__(256, 1) void gru_persist(GruParams P, unsigned* bars) {
  int unit = blockIdx.x >> 5;         // 0:f-L1 1:b-L1 2:f-L2 3:b-L2
  int cb   = (blockIdx.x & 31) << 4;  // h-column base
  int layer = unit >> 1, dir = unit & 1;
  unsigned* bar = bars + dir * 32;    // 128B apart

  int w = threadIdx.x >> 6, lane = threadIdx.x & 63;
  // wave roles: 0 -> r, 1 -> z, 2 -> n_i (x-side only), 3 -> n_h (h-side only)
  int nrow = ((w == 0) ? 0 : (w == 1) ? Hh : 2 * Hh) + cb;

  const _Float16* Wx = P.Wx[dir][layer];
  const _Float16* Wh = P.Wh[dir][layer];
  const float* bih = P.bih[dir][layer];
  const float* bhh = P.bhh[dir][layer];
  float*    h32base = P.h32[dir][layer];
  _Float16* h16base = P.h16[dir][layer];
  const _Float16* h1src = P.h16[dir][0];

  int col = lane & 15;
  float bv;
  if      (w == 0) bv = bih[cb + col] + bhh[cb + col];
  else if (w == 1) bv = bih[Hh + cb + col] + bhh[Hh + cb + col];
  else if (w == 2) bv = bih[2 * Hh + cb + col];
  else             bv = bhh[2 * Hh + cb + col];

  __shared__ float lds[4][64][16];
  int rbase = 4 * (lane >> 4);

  for (int s = 0; s <= Tt; ++s) {
    bool active = (layer == 0) ? (s < Tt) : (s > 0);
    if (active) {
      int t = (layer == 0) ? s : (s - 1);
      const float*    hprev32 = h32base + (size_t)((t & 1) ^ 1) * (Bb * Hh);
      const _Float16* hprev16 = h16base + (size_t)((t & 1) ^ 1) * (Bb * Hh);
      float*    hout32 = h32base + (size_t)(t & 1) * (Bb * Hh);
      _Float16* hout16 = h16base + (size_t)(t & 1) * (Bb * Hh);

      f32x4 acc[4] = {{0.f,0.f,0.f,0.f},{0.f,0.f,0.f,0.f},{0.f,0.f,0.f,0.f},{0.f,0.f,0.f,0.f}};
      if (w != 3) {  // x-side
        if (layer == 0) {
          int tt = dir ? (Tt - 1 - t) : t;
          mmacc<INPP, INPP, INPP>(acc, P.xt + (size_t)tt * Bb * INPP, Wx, nrow, lane);
        } else {
          mmacc<Hh, Hh, Hh>(acc, h1src + (size_t)(t & 1) * (Bb * Hh), Wx, nrow, lane);
        }
      }
      if (w != 2) {  // h-side
        mmacc<Hh, Hh, Hh>(acc, hprev16, Wh, nrow, lane);
      }
#pragma unroll
      for (int mt = 0; mt < 4; ++mt)
#pragma unroll
        for (int r = 0; r < 4; ++r)
          lds[w][mt * 16 + rbase + r][col] = acc[mt][r] + bv;
      __syncthreads();

      for (int e = threadIdx.x; e < Bb * 16; e += 256) {
        int row = e >> 4, c = e & 15;
        float rr = sigm(lds[0][row][c]);
        float zz = sigm(lds[1][row][c]);
        float nn = tanhf(lds[2][row][c] + rr * lds[3][row][c]);
        float hp = hprev32[row * Hh + cb + c];
        float hv = (1.0f - zz) * nn + zz * hp;
        hout32[row * Hh + cb + c] = hv;
        _Float16 h6 = (_Float16)hv;
        hout16[row * Hh + cb + c] = h6;
        if (layer == 1)
          P.allh[((size_t)row * Tt + t) * D2H + dir * Hh + cb + c] = h6;
      }
    }
    gridbar(bar, (unsigned)(s + 1) * 64);
  }
}

// ---------------- generic TN GEMM: C = A(MxK) * B(NxK)^T (+bias) ----------------
struct GemmArgs {
  const _Float16* A; const _Float16* Bm;
  float* Cf; _Float16* Ch;
  const float* bias;
  int lda, ldb, ldc, K;
  long long sAz, sBz, sCz;
};

__global__ __launch_bounds__(256) void gemm_tn(GemmArgs g) {
  int z = blockIdx.z;
  const _Float16* A  = g.A  + (size_t)z * g.sAz;
  const _Float16* Bm = g.Bm + (size_t)z * g.sBz;
  int m0 = blockIdx.y * 64;
  int lane = threadIdx.x & 63;
  int n0 = blockIdx.x * 64 + (threadIdx.x >> 6) * 16;

  f32x4 a0 = {0.f,0.f,0.f,0.f}, a1 = a0, a2 = a0, a3 = a0;
  for (int k0 = 0; k0 < g.K; k0 += 32) {
    f16x8 bfr = ldfrag(Bm, g.ldb, n0, k0, lane);
    a0 = __builtin_amdgcn_mfma_f32_16x16x32_f16(ldfrag(A, g.lda, m0 +  0, k0, lane), bfr, a0, 0,0,0);
    a1 = __builtin_amdgcn_mfma_f32_16x16x32_f16(ldfrag(A, g.lda, m0 + 16, k0, lane), bfr, a1, 0,0,0);
    a2 = __builtin_amdgcn_mfma_f32_16x16x32_f16(ldfrag(A, g.lda, m0 + 32, k0, lane), bfr, a2, 0,0,0);
    a3 = __builtin_amdgcn_mfma_f32_16x16x32_f16(ldfrag(A, g.lda, m0 + 48, k0, lane), bfr, a3, 0,0,0);
  }
  int col = n0 + (lane & 15);
  float bv = g.bias ? g.bias[col] : 0.0f;
  int rbase = 4 * (lane >> 4);
  f32x4 acc[4] = {a0, a1, a2, a3};
#pragma unroll
  for (int mt = 0; mt < 4; ++mt)
#pragma unroll
    for (int r = 0; r < 4; ++r) {
      int row = m0 + mt * 16 + rbase + r;
      float v = acc[mt][r] + bv;
      size_t idx = (size_t)z * g.sCz + (size_t)row * g.ldc + col;
      if (g.Cf) g.Cf[idx] = v; else g.Ch[idx] = (_Float16)v;
    }
}

// ---------------- row softmax: scores f32 (.,512) -> p f16 ----------------
__global__ __launch_bounds__(256) void softmax_rows(const float* __restrict__ sc, _Float16* __restrict__ p) {
  int row = blockIdx.x * 4 + (threadIdx.x >> 6);
  int lane = threadIdx.x & 63;
  const float* s = sc + (size_t)row * 512 + lane * 8;
  float v[8];
  float4 q0 = *(const float4*)s, q1 = *(const float4*)(s + 4);
  v[0]=q0.x; v[1]=q0.y; v[2]=q0.z; v[3]=q0.w; v[4]=q1.x; v[5]=q1.y; v[6]=q1.z; v[7]=q1.w;
  float mx = v[0];
#pragma unroll
  for (int j = 1; j < 8; ++j) mx = fmaxf(mx, v[j]);
  for (int o = 32; o; o >>= 1) mx = fmaxf(mx, __shfl_xor(mx, o));
  float sum = 0.f;
#pragma unroll
  for (int j = 0; j < 8; ++j) { v[j] = expf(v[j] - mx); sum += v[j]; }
  for (int o = 32; o; o >>= 1) sum += __shfl_xor(sum, o);
  float inv = 1.0f / sum;
  _Float16* pd = p + (size_t)row * 512 + lane * 8;
#pragma unroll
  for (int j = 0; j < 8; ++j) pd[j] = (_Float16)(v[j] * inv);
}

// ---------------- per-batch transpose: allhT[b][d][t] = allh[b][t][d] ----------------
__global__ void transpose_bt(const _Float16* __restrict__ allh, _Float16* __restrict__ allhT) {
  __shared__ _Float16 tile[32][33];
  int b = blockIdx.z;
  int d0 = blockIdx.x * 32, t0 = blockIdx.y * 32;
  int tx = threadIdx.x, ty = threadIdx.y;  // (32, 8)
  const _Float16* in = allh + (size_t)b * Tt * D2H;
  _Float16* outp = allhT + (size_t)b * D2H * Tt;
#pragma unroll
  for (int j = 0; j < 4; ++j)
    tile[ty + 8 * j][tx] = in[(size_t)(t0 + ty + 8 * j) * D2H + d0 + tx];
  __syncthreads();
#pragma unroll
  for (int j = 0; j < 4; ++j)
    outp[(size_t)(d0 + ty + 8 * j) * Tt + t0 + tx] = tile[tx][ty + 8 * j];
}

// ---------------- fused g/f GEMM + gating epilogue -> attn (f32) ----------------
__global__ __launch_bounds__(256) void gf_fused(const _Float16* __restrict__ ctx,
                                                const _Float16* __restrict__ allh,
                                                const _Float16* __restrict__ Wgf,
                                                const float* __restrict__ bg,
                                                const float* __restrict__ bfv,
                                                float* __restrict__ out_attn) {
  int m0 = blockIdx.y * 64;
  int cb = blockIdx.x * 32;
  int w = threadIdx.x >> 6, lane = threadIdx.x & 63;
  int nrow = (w >> 1) * 1024 + cb + (w & 1) * 16;  // w0,w1: g cols; w2,w3: f cols

  f32x4 a0 = {0.f,0.f,0.f,0.f}, a1 = a0, a2 = a0, a3 = a0;
  for (int k0 = 0; k0 < 1024; k0 += 32) {   // phase 1: cat[:,0:1024] = ctx
    f16x8 bfr = ldfrag(Wgf, 2048, nrow, k0, lane);
    a0 = __builtin_amdgcn_mfma_f32_16x16x32_f16(ldfrag(ctx, 1024, m0 +  0, k0, lane), bfr, a0, 0,0,0);
    a1 = __builtin_amdgcn_mfma_f32_16x16x32_f16(ldfrag(ctx, 1024, m0 + 16, k0, lane), bfr, a1, 0,0,0);
    a2 = __builtin_amdgcn_mfma_f32_16x16x32_f16(ldfrag(ctx, 1024, m0 + 32, k0, lane), bfr, a2, 0,0,0);
    a3 = __builtin_amdgcn_mfma_f32_16x16x32_f16(ldfrag(ctx, 1024, m0 + 48, k0, lane), bfr, a3, 0,0,0);
  }
  for (int k0 = 0; k0 < 1024; k0 += 32) {   // phase 2: cat[:,1024:2048] = all_h
    f16x8 bfr = ldfrag(Wgf, 2048, nrow, 1024 + k0, lane);
    a0 = __builtin_amdgcn_mfma_f32_16x16x32_f16(ldfrag(allh, 1024, m0 +  0, k0, lane), bfr, a0, 0,0,0);
    a1 = __builtin_amdgcn_mfma_f32_16x16x32_f16(ldfrag(allh, 1024, m0 + 16, k0, lane), bfr, a1, 0,0,0);
    a2 = __builtin_amdgcn_mfma_f32_16x16x32_f16(ldfrag(allh, 1024, m0 + 32, k0, lane), bfr, a2, 0,0,0);
    a3 = __builtin_amdgcn_mfma_f32_16x16x32_f16(ldfrag(allh, 1024, m0 + 48, k0, lane), bfr, a3, 0,0,0);
  }
  int col = lane & 15;
  int n = nrow + col;
  float bv = (n < 1024) ? bg[n] : bfv[n - 1024];

  __shared__ float lds[4][64][16];
  int rbase = 4 * (lane >> 4);
  f32x4 acc[4] = {a0, a1, a2, a3};
#pragma unroll
  for (int mt = 0; mt < 4; ++mt)
#pragma unroll
    for (int r = 0; r < 4; ++r)
      lds[w][mt * 16 + rbase + r][col] = acc[mt][r] + bv;
  __syncthreads();

  for (int e = threadIdx.x; e < 64 * 32; e += 256) {
    int row = e >> 5, c = e & 31;
    float gv = lds[c >> 4][row][c & 15];
    float fv = lds[2 + (c >> 4)][row][c & 15];
    float gg = sigm(gv);
    float ff = tanhf(fv);
    int m = m0 + row, cg = cb + c;
    float ah = (float)allh[(size_t)m * D2H + cg];
    out_attn[(size_t)m * D2H + cg] = gg * ff + (1.0f - gg) * ah;
  }
}

// ---------------- final concat output ----------------
__global__ void write_concat(const float* __restrict__ h1f, const float* __restrict__ h1b,
                             float* __restrict__ out) {
  int i = blockIdx.x * 256 + threadIdx.x;
  if (i >= Bb * D2H) return;
  int b = i >> 10, c = i & 1023;
  out[i] = (c < Hh) ? h1f[b * Hh + c] : h1b[b * Hh + (c - Hh)];
}

// =============================== host ===============================
extern "C" void kernel_launch(void* const* d_in, const int* in_sizes, int n_in,
                              void* d_out, int out_size, void* d_ws, size_t ws_size,
                              hipStream_t stream) {
  const int*   context = (const int*)d_in[0];
  const int*   tags    = (const int*)d_in[1];
  const float* glove   = (const float*)d_in[2];
  const float* bio     = (const float*)d_in[3];
  const float* b_lin   = (const float*)d_in[21];
  const float* b_g     = (const float*)d_in[23];
  const float* b_f     = (const float*)d_in[25];

  char* ws = (char*)d_ws;
  size_t off = 0;
  auto carve = [&](size_t bytes) -> void* {
    void* pp = ws + off;
    off = (off + bytes + 255) & ~(size_t)255;
    return pp;
  };

  _Float16* xt = (_Float16*)carve((size_t)Tt * Bb * INPP * 2);
  _Float16 *Wx16[2][2], *Wh16[2][2];
  Wx16[0][0] = (_Float16*)carve((size_t)1536 * 320 * 2);
  Wx16[1][0] = (_Float16*)carve((size_t)1536 * 320 * 2);
  Wx16[0][1] = (_Float16*)carve((size_t)1536 * 512 * 2);
  Wx16[1][1] = (_Float16*)carve((size_t)1536 * 512 * 2);
  for (int d = 0; d < 2; ++d)
    for (int l = 0; l < 2; ++l) Wh16[d][l] = (_Float16*)carve((size_t)1536 * 512 * 2);
  _Float16* wlin = (_Float16*)carve((size_t)1024 * 1024 * 2);
  _Float16* wgf  = (_Float16*)carve((size_t)2048 * 2048 * 2);
  _Float16* allh  = (_Float16*)carve((size_t)Bb * Tt * D2H * 2);
  _Float16* allhT = (_Float16*)carve((size_t)Bb * Tt * D2H * 2);
  _Float16* qctx  = (_Float16*)carve((size_t)Bb * Tt * D2H * 2);   // q, then reused as ctx
  float*    scores = (float*)carve((size_t)Bb * Tt * Tt * 4);
  _Float16* pmat   = (_Float16*)carve((size_t)Bb * Tt * Tt * 2);
  float*    h32buf = (float*)carve((size_t)2 * 2 * 2 * Bb * Hh * 4);
  _Float16* h16buf = (_Float16*)carve((size_t)2 * 2 * 2 * Bb * Hh * 2);
  unsigned* bars   = (unsigned*)carve(256);

  // zero recurrent state (both slots) + barrier counters
  hipMemsetAsync(h32buf, 0, (size_t)2 * 2 * 2 * Bb * Hh * 4, stream);
  hipMemsetAsync(h16buf, 0, (size_t)2 * 2 * 2 * Bb * Hh * 2, stream);
  hipMemsetAsync(bars, 0, 256, stream);

  auto conv = [&](const void* src, _Float16* dst, int rows, int csrc, int cdst) {
    int total = rows * cdst;
    convert_pad<<<(total + 255) / 256, 256, 0, stream>>>((const float*)src, dst, rows, csrc, cdst);
  };
  conv(d_in[4],  Wx16[0][0], 1536, 303, 320);
  conv(d_in[12], Wx16[1][0], 1536, 303, 320);
  conv(d_in[8],  Wx16[0][1], 1536, 512, 512);
  conv(d_in[16], Wx16[1][1], 1536, 512, 512);
  conv(d_in[5],  Wh16[0][0], 1536, 512, 512);
  conv(d_in[13], Wh16[1][0], 1536, 512, 512);
  conv(d_in[9],  Wh16[0][1], 1536, 512, 512);
  conv(d_in[17], Wh16[1][1], 1536, 512, 512);
  conv(d_in[20], wlin, 1024, 1024, 1024);
  conv(d_in[22], wgf, 1024, 2048, 2048);
  conv(d_in[24], wgf + (size_t)1024 * 2048, 1024, 2048, 2048);

  embed_kernel<<<Tt * Bb, 64, 0, stream>>>(context, tags, glove, bio, xt);

  GruParams GP;
  GP.xt = xt;
  GP.Wx[0][0] = Wx16[0][0]; GP.Wx[0][1] = Wx16[0][1]; GP.Wx[1][0] = Wx16[1][0]; GP.Wx[1][1] = Wx16[1][1];
  GP.Wh[0][0] = Wh16[0][0]; GP.Wh[0][1] = Wh16[0][1]; GP.Wh[1][0] = Wh16[1][0]; GP.Wh[1][1] = Wh16[1][1];
  GP.bih[0][0] = (const float*)d_in[6];  GP.bhh[0][0] = (const float*)d_in[7];
  GP.bih[0][1] = (const float*)d_in[10]; GP.bhh[0][1] = (const float*)d_in[11];
  GP.bih[1][0] = (const float*)d_in[14]; GP.bhh[1][0] = (const float*)d_in[15];
  GP.bih[1][1] = (const float*)d_in[18]; GP.bhh[1][1] = (const float*)d_in[19];
  for (int d = 0; d < 2; ++d)
    for (int l = 0; l < 2; ++l) {
      GP.h32[d][l] = h32buf + (size_t)((d * 2 + l) * 2) * Bb * Hh;
      GP.h16[d][l] = h16buf + (size_t)((d * 2 + l) * 2) * Bb * Hh;
    }
  GP.allh = allh;

  gru_persist<<<128, 256, 0, stream>>>(GP, bars);

  // q = all_h @ W_lin^T + b_lin  -> f16
  GemmArgs ga;
  ga.A = allh; ga.lda = 1024; ga.sAz = 0;
  ga.Bm = wlin; ga.ldb = 1024; ga.sBz = 0;
  ga.bias = b_lin; ga.Cf = nullptr; ga.Ch = qctx; ga.ldc = 1024; ga.sCz = 0; ga.K = 1024;
  gemm_tn<<<dim3(16, 512, 1), 256, 0, stream>>>(ga);

  // scores[b] = q[b] @ all_h[b]^T -> f32
  ga.A = qctx; ga.lda = 1024; ga.sAz = (long long)512 * 1024;
  ga.Bm = allh; ga.ldb = 1024; ga.sBz = (long long)512 * 1024;
  ga.bias = nullptr; ga.Cf = scores; ga.Ch = nullptr; ga.ldc = 512; ga.sCz = (long long)512 * 512; ga.K = 1024;
  gemm_tn<<<dim3(8, 8, 64), 256, 0, stream>>>(ga);

  softmax_rows<<<(Bb * Tt) / 4, 256, 0, stream>>>(scores, pmat);

  transpose_bt<<<dim3(32, 16, 64), dim3(32, 8), 0, stream>>>(allh, allhT);

  // ctx[b] = p[b] @ (all_hT[b])^T  -> f16 (overwrites q)
  ga.A = pmat; ga.lda = 512; ga.sAz = (long long)512 * 512;
  ga.Bm = allhT; ga.ldb = 512; ga.sBz = (long long)1024 * 512;
  ga.bias = nullptr; ga.Cf = nullptr; ga.Ch = qctx; ga.ldc = 1024; ga.sCz = (long long)512 * 1024; ga.K = 512;
  gemm_tn<<<dim3(16, 8, 64), 256, 0, stream>>>(ga);

  float* out_attn = (float*)d_out + (size_t)Bb * D2H;
  gf_fused<<<dim3(32, 512), 256, 0, stream>>>(qctx, allh, wgf, b_g, b_f, out_attn);

  const float* h1f_fin = h32buf + (size_t)((0 * 2 + 0) * 2 + 1) * Bb * Hh;  // dir 0, layer 0, slot 1 (t=511)
  const float* h1b_fin = h32buf + (size_t)((1 * 2 + 0) * 2 + 1) * Bb * Hh;
  write_concat<<<(Bb * D2H + 255) / 256, 256, 0, stream>>>(h1f_fin, h1b_fin, (float*)d_out);
}

// Round 3
// 12408.902 us; speedup vs baseline: 1.2833x; 1.2833x over previous
//
#include <hip/hip_runtime.h>
#include <hip/hip_bf16.h>
#include <math.h>

typedef _Float16 f16x8 __attribute__((ext_vector_type(8)));
typedef float    f32x4 __attribute__((ext_vector_type(4)));

#define DEV __device__ __forceinline__

static constexpr int Ee   = 300;   // glove dim
static constexpr int INP  = 303;   // E + 3
static constexpr int INPP = 320;   // padded input dim
static constexpr int Hh   = 512;
static constexpr int Bb   = 64;
static constexpr int Tt   = 512;
static constexpr int D2H  = 1024;  // 2H
static constexpr int SLAB = Bb * Hh;  // one h-state slab (elements)

// ---- MFMA fragment load: K-major matrix M[row][k], frag[l][j] = M[row0+(l&15)][k0+8*(l>>4)+j]
DEV f16x8 ldfrag(const _Float16* base, int ld, int row0, int k0, int lane) {
  return *reinterpret_cast<const f16x8*>(base + (size_t)(row0 + (lane & 15)) * ld + (k0 + 8 * (lane >> 4)));
}
DEV float sigm(float x) { return 1.0f / (1.0f + expf(-x)); }

// ---------------- weight convert (f32 -> f16, optional column pad) ----------------
__global__ void convert_pad(const float* __restrict__ src, _Float16* __restrict__ dst,
                            int rows, int csrc, int cdst) {
  int i = blockIdx.x * 256 + threadIdx.x;
  if (i >= rows * cdst) return;
  int r = i / cdst, c = i - r * cdst;
  dst[i] = (c < csrc) ? (_Float16)src[(size_t)r * csrc + c] : (_Float16)0.0f;
}

// ---------------- embedding: xt (T, B, INPP) f16 ----------------
__global__ void embed_kernel(const int* __restrict__ context, const int* __restrict__ tags,
                             const float* __restrict__ glove, const float* __restrict__ bio,
                             _Float16* __restrict__ xt) {
  int blk = blockIdx.x;            // t*64 + b
  int t = blk >> 6, b = blk & 63;
  int cid = context[b * Tt + t];   // context (B,T,1)
  int tag = tags[b * Tt + t];      // (B,T)
  _Float16* dst = xt + (size_t)blk * INPP;
  for (int c = threadIdx.x; c < INPP; c += 64) {
    float v = (c < Ee) ? glove[(size_t)cid * Ee + c]
                       : ((c < INP) ? bio[tag * 3 + (c - Ee)] : 0.0f);
    dst[c] = (_Float16)v;
  }
}

// ---------------- persistent GRU recurrence (fence-free) ----------------
// unit = layer*2 + dir. hb slabs: hb + ((size_t)t*4 + unit)*SLAB holds h_{t-1}
// (slab t=0 is zeros). Step t reads slab t, write-through publishes slab t+1.
struct GruParams {
  const _Float16* xt;
  const _Float16* Wx[4];   // input-side weights (ld = 320 for L1, 512 for L2)
  const _Float16* Wh[4];   // hidden-side weights (ld = 512)
  const float* bih[4];
  const float* bhh[4];
  _Float16* hb;            // fresh h16 slabs, (Tt+1) x 4 x SLAB
  _Float16* allh;          // (B, T, 2H) f16
  float*    h1fin;         // [dir][64][512] fp32 layer-1 final states
};

// acc += A(64xKX, ld=LDA) * B(rows nrow.., ld=LDB)^T
template<int KX, int LDA, int LDB>
DEV void mmacc(f32x4* acc, const _Float16* __restrict__ A,
               const _Float16* __restrict__ Bm, int nrow, int lane) {
  const _Float16* arow = A + (size_t)(lane & 15) * LDA + 8 * (lane >> 4);
  const _Float16* brow = Bm + (size_t)(nrow + (lane & 15)) * LDB + 8 * (lane >> 4);
#pragma unroll 4
  for (int k0 = 0; k0 < KX; k0 += 32) {
    f16x8 bfr = *(const f16x8*)(brow + k0);
#pragma unroll
    for (int mt = 0; mt < 4; ++mt) {
      f16x8 afr = *(const f16x8*)(arow + (size_t)mt * 16 * LDA + k0);
      acc[mt] = __builtin_amdgcn_mfma_f32_16x16x32_f16(afr, bfr, acc[mt], 0, 0, 0);
    }
  }
}

__global__ __launch_bounds__(256, 1) void gru_persist(GruParams P, unsigned* cnt) {
  int unit = blockIdx.x >> 5;         // layer*2 + dir
  int cb   = (blockIdx.x & 31) << 4;  // h-column base
  int layer = unit >> 1, dir = unit & 1;
  unsigned* myCnt = cnt + unit * 32;  // 128B apart
  unsigned* l1Cnt = cnt + dir * 32;   // L1 unit of same dir

  int w = threadIdx.x >> 6, lane = threadIdx.x & 63;
  // wave roles: 0 -> r, 1 -> z, 2 -> n_i (x-side only), 3 -> n_h (h-side only)
  int nrow = ((w == 0) ? 0 : (w == 1) ? Hh : 2 * Hh) + cb;

  const _Float16* Wx = P.Wx[unit];
  const _Float16* Wh = P.Wh[unit];
  const float* bih = P.bih[unit];
  const float* bhh = P.bhh[unit];

  int col = lane & 15;
  float bv;
  if      (w == 0) bv = bih[cb + col] + bhh[cb + col];
  else if (w == 1) bv = bih[Hh + cb + col] + bhh[Hh + cb + col];
  else if (w == 2) bv = bih[2 * Hh + cb + col];
  else             bv = bhh[2 * Hh + cb + col];

  __shared__ float gl[4][64][16];   // gate pre-activations
  __shared__ float h32[64][16];     // block-private fp32 h state
  for (int e = threadIdx.x; e < 64 * 16; e += 256) ((float*)h32)[e] = 0.0f;
  __syncthreads();

  int rbase = 4 * (lane >> 4);
  int erow = threadIdx.x >> 2, ec0 = (threadIdx.x & 3) << 2;  // epilogue: 4 cols/thread

  for (int t = 0; t < Tt; ++t) {
    // ---- wait for dependencies (relaxed polls at LLC; no cache flushes) ----
    if (threadIdx.x == 0) {
      unsigned tgt = 32u * (unsigned)t;
      while (__hip_atomic_load(myCnt, __ATOMIC_RELAXED, __HIP_MEMORY_SCOPE_AGENT) < tgt)
        __builtin_amdgcn_s_sleep(2);
      if (layer == 1) {
        unsigned tgt2 = 32u * (unsigned)(t + 1);
        while (__hip_atomic_load(l1Cnt, __ATOMIC_RELAXED, __HIP_MEMORY_SCOPE_AGENT) < tgt2)
          __builtin_amdgcn_s_sleep(2);
      }
    }
    __syncthreads();

    const _Float16* hprev = P.hb + ((size_t)t * 4 + unit) * SLAB;

    f32x4 acc[4] = {{0.f,0.f,0.f,0.f},{0.f,0.f,0.f,0.f},{0.f,0.f,0.f,0.f},{0.f,0.f,0.f,0.f}};
    if (w != 3) {  // x-side
      if (layer == 0) {
        int tt = dir ? (Tt - 1 - t) : t;
        mmacc<INPP, INPP, INPP>(acc, P.xt + (size_t)tt * Bb * INPP, Wx, nrow, lane);
      } else {
        mmacc<Hh, Hh, Hh>(acc, P.hb + ((size_t)(t + 1) * 4 + dir) * SLAB, Wx, nrow, lane);
      }
    }
    if (w != 2) {  // h-side
      mmacc<Hh, Hh, Hh>(acc, hprev, Wh, nrow, lane);
    }
#pragma unroll
    for (int mt = 0; mt < 4; ++mt)
#pragma unroll
      for (int r = 0; r < 4; ++r)
        gl[w][mt * 16 + rbase + r][col] = acc[mt][r] + bv;
    __syncthreads();

    // ---- epilogue: gates -> new h; publish write-through ----
    union { _Float16 h[4]; unsigned long long u; } pk;
    float hv[4];
#pragma unroll
    for (int j = 0; j < 4; ++j) {
      int c = ec0 + j;
      float rr = sigm(gl[0][erow][c]);
      float zz = sigm(gl[1][erow][c]);
      float nn = tanhf(gl[2][erow][c] + rr * gl[3][erow][c]);
      float hp = h32[erow][c];
      hv[j] = (1.0f - zz) * nn + zz * hp;
      h32[erow][c] = hv[j];
      pk.h[j] = (_Float16)hv[j];
    }
    _Float16* hout = P.hb + ((size_t)(t + 1) * 4 + unit) * SLAB + erow * Hh + cb + ec0;
    __hip_atomic_store((unsigned long long*)hout, pk.u, __ATOMIC_RELAXED, __HIP_MEMORY_SCOPE_AGENT);
    if (layer == 1)
      *(unsigned long long*)(P.allh + ((size_t)erow * Tt + t) * D2H + dir * Hh + cb + ec0) = pk.u;
    if (layer == 0 && t == Tt - 1)
      *(float4*)(P.h1fin + ((size_t)dir * Bb + erow) * Hh + cb + ec0) = make_float4(hv[0], hv[1], hv[2], hv[3]);

    asm volatile("s_waitcnt vmcnt(0)" ::: "memory");  // write-through stores visible at LLC
    __syncthreads();
    if (threadIdx.x == 0)
      __hip_atomic_fetch_add(myCnt, 1u, __ATOMIC_RELAXED, __HIP_MEMORY_SCOPE_AGENT);
  }
}

// ---------------- generic TN GEMM: C = A(MxK) * B(NxK)^T (+bias) ----------------
struct GemmArgs {
  const _Float16* A; const _Float16* Bm;
  float* Cf; _Float16* Ch;
  const float* bias;
  int lda, ldb, ldc, K;
  long long sAz, sBz, sCz;
};

__global__ __launch_bounds__(256) void gemm_tn(GemmArgs g) {
  int z = blockIdx.z;
  const _Float16* A  = g.A  + (size_t)z * g.sAz;
  const _Float16* Bm = g.Bm + (size_t)z * g.sBz;
  int m0 = blockIdx.y * 64;
  int lane = threadIdx.x & 63;
  int n0 = blockIdx.x * 64 + (threadIdx.x >> 6) * 16;

  f32x4 a0 = {0.f,0.f,0.f,0.f}, a1 = a0, a2 = a0, a3 = a0;
  for (int k0 = 0; k0 < g.K; k0 += 32) {
    f16x8 bfr = ldfrag(Bm, g.ldb, n0, k0, lane);
    a0 = __builtin_amdgcn_mfma_f32_16x16x32_f16(ldfrag(A, g.lda, m0 +  0, k0, lane), bfr, a0, 0,0,0);
    a1 = __builtin_amdgcn_mfma_f32_16x16x32_f16(ldfrag(A, g.lda, m0 + 16, k0, lane), bfr, a1, 0,0,0);
    a2 = __builtin_amdgcn_mfma_f32_16x16x32_f16(ldfrag(A, g.lda, m0 + 32, k0, lane), bfr, a2, 0,0,0);
    a3 = __builtin_amdgcn_mfma_f32_16x16x32_f16(ldfrag(A, g.lda, m0 + 48, k0, lane), bfr, a3, 0,0,0);
  }
  int col = n0 + (lane & 15);
  float bv = g.bias ? g.bias[col] : 0.0f;
  int rbase = 4 * (lane >> 4);
  f32x4 acc[4] = {a0, a1, a2, a3};
#pragma unroll
  for (int mt = 0; mt < 4; ++mt)
#pragma unroll
    for (int r = 0; r < 4; ++r) {
      int row = m0 + mt * 16 + rbase + r;
      float v = acc[mt][r] + bv;
      size_t idx = (size_t)z * g.sCz + (size_t)row * g.ldc + col;
      if (g.Cf) g.Cf[idx] = v; else g.Ch[idx] = (_Float16)v;
    }
}

// ---------------- row softmax: scores f32 (.,512) -> p f16 ----------------
__global__ __launch_bounds__(256) void softmax_rows(const float* __restrict__ sc, _Float16* __restrict__ p) {
  int row = blockIdx.x * 4 + (threadIdx.x >> 6);
  int lane = threadIdx.x & 63;
  const float* s = sc + (size_t)row * 512 + lane * 8;
  float v[8];
  float4 q0 = *(const float4*)s, q1 = *(const float4*)(s + 4);
  v[0]=q0.x; v[1]=q0.y; v[2]=q0.z; v[3]=q0.w; v[4]=q1.x; v[5]=q1.y; v[6]=q1.z; v[7]=q1.w;
  float mx = v[0];
#pragma unroll
  for (int j = 1; j < 8; ++j) mx = fmaxf(mx, v[j]);
  for (int o = 32; o; o >>= 1) mx = fmaxf(mx, __shfl_xor(mx, o));
  float sum = 0.f;
#pragma unroll
  for (int j = 0; j < 8; ++j) { v[j] = expf(v[j] - mx); sum += v[j]; }
  for (int o = 32; o; o >>= 1) sum += __shfl_xor(sum, o);
  float inv = 1.0f / sum;
  _Float16* pd = p + (size_t)row * 512 + lane * 8;
#pragma unroll
  for (int j = 0; j < 8; ++j) pd[j] = (_Float16)(v[j] * inv);
}

// ---------------- per-batch transpose: allhT[b][d][t] = allh[b][t][d] ----------------
__global__ void transpose_bt(const _Float16* __restrict__ allh, _Float16* __restrict__ allhT) {
  __shared__ _Float16 tile[32][33];
  int b = blockIdx.z;
  int d0 = blockIdx.x * 32, t0 = blockIdx.y * 32;
  int tx = threadIdx.x, ty = threadIdx.y;  // (32, 8)
  const _Float16* in = allh + (size_t)b * Tt * D2H;
  _Float16* outp = allhT + (size_t)b * D2H * Tt;
#pragma unroll
  for (int j = 0; j < 4; ++j)
    tile[ty + 8 * j][tx] = in[(size_t)(t0 + ty + 8 * j) * D2H + d0 + tx];
  __syncthreads();
#pragma unroll
  for (int j = 0; j < 4; ++j)
    outp[(size_t)(d0 + ty + 8 * j) * Tt + t0 + tx] = tile[tx][ty + 8 * j];
}

// ---------------- fused g/f GEMM + gating epilogue -> attn (f32) ----------------
__global__ __launch_bounds__(256) void gf_fused(const _Float16* __restrict__ ctx,
                                                const _Float16* __restrict__ allh,
                                                const _Float16* __restrict__ Wgf,
                                                const float* __restrict__ bg,
                                                const float* __restrict__ bfv,
                                                float* __restrict__ out_attn) {
  int m0 = blockIdx.y * 64;
  int cb = blockIdx.x * 32;
  int w = threadIdx.x >> 6, lane = threadIdx.x & 63;
  int nrow = (w >> 1) * 1024 + cb + (w & 1) * 16;  // w0,w1: g cols; w2,w3: f cols

  f32x4 a0 = {0.f,0.f,0.f,0.f}, a1 = a0, a2 = a0, a3 = a0;
  for (int k0 = 0; k0 < 1024; k0 += 32) {   // phase 1: cat[:,0:1024] = ctx
    f16x8 bfr = ldfrag(Wgf, 2048, nrow, k0, lane);
    a0 = __builtin_amdgcn_mfma_f32_16x16x32_f16(ldfrag(ctx, 1024, m0 +  0, k0, lane), bfr, a0, 0,0,0);
    a1 = __builtin_amdgcn_mfma_f32_16x16x32_f16(ldfrag(ctx, 1024, m0 + 16, k0, lane), bfr, a1, 0,0,0);
    a2 = __builtin_amdgcn_mfma_f32_16x16x32_f16(ldfrag(ctx, 1024, m0 + 32, k0, lane), bfr, a2, 0,0,0);
    a3 = __builtin_amdgcn_mfma_f32_16x16x32_f16(ldfrag(ctx, 1024, m0 + 48, k0, lane), bfr, a3, 0,0,0);
  }
  for (int k0 = 0; k0 < 1024; k0 += 32) {   // phase 2: cat[:,1024:2048] = all_h
    f16x8 bfr = ldfrag(Wgf, 2048, nrow, 1024 + k0, lane);
    a0 = __builtin_amdgcn_mfma_f32_16x16x32_f16(ldfrag(allh, 1024, m0 +  0, k0, lane), bfr, a0, 0,0,0);
    a1 = __builtin_amdgcn_mfma_f32_16x16x32_f16(ldfrag(allh, 1024, m0 + 16, k0, lane), bfr, a1, 0,0,0);
    a2 = __builtin_amdgcn_mfma_f32_16x16x32_f16(ldfrag(allh, 1024, m0 + 32, k0, lane), bfr, a2, 0,0,0);
    a3 = __builtin_amdgcn_mfma_f32_16x16x32_f16(ldfrag(allh, 1024, m0 + 48, k0, lane), bfr, a3, 0,0,0);
  }
  int col = lane & 15;
  int n = nrow + col;
  float bv = (n < 1024) ? bg[n] : bfv[n - 1024];

  __shared__ float lds[4][64][16];
  int rbase = 4 * (lane >> 4);
  f32x4 acc[4] = {a0, a1, a2, a3};
#pragma unroll
  for (int mt = 0; mt < 4; ++mt)
#pragma unroll
    for (int r = 0; r < 4; ++r)
      lds[w][mt * 16 + rbase + r][col] = acc[mt][r] + bv;
  __syncthreads();

  for (int e = threadIdx.x; e < 64 * 32; e += 256) {
    int row = e >> 5, c = e & 31;
    float gv = lds[c >> 4][row][c & 15];
    float fv = lds[2 + (c >> 4)][row][c & 15];
    float gg = sigm(gv);
    float ff = tanhf(fv);
    int m = m0 + row, cg = cb + c;
    float ah = (float)allh[(size_t)m * D2H + cg];
    out_attn[(size_t)m * D2H + cg] = gg * ff + (1.0f - gg) * ah;
  }
}

// ---------------- final concat output ----------------
__global__ void write_concat(const float* __restrict__ h1fin, float* __restrict__ out) {
  int i = blockIdx.x * 256 + threadIdx.x;
  if (i >= Bb * D2H) return;
  int b = i >> 10, c = i & 1023;
  // h1fin: [dir][64][512]
  out[i] = (c < Hh) ? h1fin[(size_t)b * Hh + c] : h1fin[(size_t)(Bb + b) * Hh + (c - Hh)];
}

// =============================== host ===============================
extern "C" void kernel_launch(void* const* d_in, const int* in_sizes, int n_in,
                              void* d_out, int out_size, void* d_ws, size_t ws_size,
                              hipStream_t stream) {
  const int*   context = (const int*)d_in[0];
  const int*   tags    = (const int*)d_in[1];
  const float* glove   = (const float*)d_in[2];
  const float* bio     = (const float*)d_in[3];
  const float* b_lin   = (const float*)d_in[21];
  const float* b_g     = (const float*)d_in[23];
  const float* b_f     = (const float*)d_in[25];

  char* ws = (char*)d_ws;
  size_t off = 0;
  auto carve = [&](size_t bytes) -> void* {
    void* pp = ws + off;
    off = (off + bytes + 255) & ~(size_t)255;
    return pp;
  };

  _Float16* xt = (_Float16*)carve((size_t)Tt * Bb * INPP * 2);
  _Float16 *Wx16[2][2], *Wh16[2][2];
  Wx16[0][0] = (_Float16*)carve((size_t)1536 * 320 * 2);
  Wx16[1][0] = (_Float16*)carve((size_t)1536 * 320 * 2);
  Wx16[0][1] = (_Float16*)carve((size_t)1536 * 512 * 2);
  Wx16[1][1] = (_Float16*)carve((size_t)1536 * 512 * 2);
  for (int d = 0; d < 2; ++d)
    for (int l = 0; l < 2; ++l) Wh16[d][l] = (_Float16*)carve((size_t)1536 * 512 * 2);
  _Float16* wlin = (_Float16*)carve((size_t)1024 * 1024 * 2);
  _Float16* wgf  = (_Float16*)carve((size_t)2048 * 2048 * 2);
  _Float16* allh  = (_Float16*)carve((size_t)Bb * Tt * D2H * 2);
  _Float16* allhT = (_Float16*)carve((size_t)Bb * Tt * D2H * 2);   // also hosts hb during recurrence
  _Float16* qctx  = (_Float16*)carve((size_t)Bb * Tt * D2H * 2);   // q, then reused as ctx
  float*    scores = (float*)carve((size_t)Bb * Tt * Tt * 4);
  _Float16* pmat   = (_Float16*)carve((size_t)Bb * Tt * Tt * 2);
  float*    h1fin  = (float*)carve((size_t)2 * Bb * Hh * 4);
  unsigned* cnt    = (unsigned*)carve(512);

  // hb (fresh h16 slabs) aliases the post-recurrence region [allhT .. pmat]:
  // needs (Tt+1)*4*SLAB*2 = 134.5 MB; region provides ~235 MB. Lifetimes disjoint.
  _Float16* hb = allhT;

  hipMemsetAsync(hb, 0, (size_t)4 * SLAB * 2, stream);  // slab t=0 (4 units) = h_{-1} = 0
  hipMemsetAsync(cnt, 0, 512, stream);                  // progress counters

  auto conv = [&](const void* src, _Float16* dst, int rows, int csrc, int cdst) {
    int total = rows * cdst;
    convert_pad<<<(total + 255) / 256, 256, 0, stream>>>((const float*)src, dst, rows, csrc, cdst);
  };
  conv(d_in[4],  Wx16[0][0], 1536, 303, 320);
  conv(d_in[12], Wx16[1][0], 1536, 303, 320);
  conv(d_in[8],  Wx16[0][1], 1536, 512, 512);
  conv(d_in[16], Wx16[1][1], 1536, 512, 512);
  conv(d_in[5],  Wh16[0][0], 1536, 512, 512);
  conv(d_in[13], Wh16[1][0], 1536, 512, 512);
  conv(d_in[9],  Wh16[0][1], 1536, 512, 512);
  conv(d_in[17], Wh16[1][1], 1536, 512, 512);
  conv(d_in[20], wlin, 1024, 1024, 1024);
  conv(d_in[22], wgf, 1024, 2048, 2048);
  conv(d_in[24], wgf + (size_t)1024 * 2048, 1024, 2048, 2048);

  embed_kernel<<<Tt * Bb, 64, 0, stream>>>(context, tags, glove, bio, xt);

  GruParams GP;
  GP.xt = xt;
  // unit = layer*2 + dir
  GP.Wx[0] = Wx16[0][0]; GP.Wx[1] = Wx16[1][0]; GP.Wx[2] = Wx16[0][1]; GP.Wx[3] = Wx16[1][1];
  GP.Wh[0] = Wh16[0][0]; GP.Wh[1] = Wh16[1][0]; GP.Wh[2] = Wh16[0][1]; GP.Wh[3] = Wh16[1][1];
  GP.bih[0] = (const float*)d_in[6];  GP.bhh[0] = (const float*)d_in[7];
  GP.bih[1] = (const float*)d_in[14]; GP.bhh[1] = (const float*)d_in[15];
  GP.bih[2] = (const float*)d_in[10]; GP.bhh[2] = (const float*)d_in[11];
  GP.bih[3] = (const float*)d_in[18]; GP.bhh[3] = (const float*)d_in[19];
  GP.hb = hb;
  GP.allh = allh;
  GP.h1fin = h1fin;

  gru_persist<<<128, 256, 0, stream>>>(GP, cnt);

  // q = all_h @ W_lin^T + b_lin  -> f16
  GemmArgs ga;
  ga.A = allh; ga.lda = 1024; ga.sAz = 0;
  ga.Bm = wlin; ga.ldb = 1024; ga.sBz = 0;
  ga.bias = b_lin; ga.Cf = nullptr; ga.Ch = qctx; ga.ldc = 1024; ga.sCz = 0; ga.K = 1024;
  gemm_tn<<<dim3(16, 512, 1), 256, 0, stream>>>(ga);

  // scores[b] = q[b] @ all_h[b]^T -> f32
  ga.A = qctx; ga.lda = 1024; ga.sAz = (long long)512 * 1024;
  ga.Bm = allh; ga.ldb = 1024; ga.sBz = (long long)512 * 1024;
  ga.bias = nullptr; ga.Cf = scores; ga.Ch = nullptr; ga.ldc = 512; ga.sCz = (long long)512 * 512; ga.K = 1024;
  gemm_tn<<<dim3(8, 8, 64), 256, 0, stream>>>(ga);

  softmax_rows<<<(Bb * Tt) / 4, 256, 0, stream>>>(scores, pmat);

  transpose_bt<<<dim3(32, 16, 64), dim3(32, 8), 0, stream>>>(allh, allhT);

  // ctx[b] = p[b] @ (all_hT[b])^T  -> f16 (overwrites q)
  ga.A = pmat; ga.lda = 512; ga.sAz = (long long)512 * 512;
  ga.Bm = allhT; ga.ldb = 512; ga.sBz = (long long)1024 * 512;
  ga.bias = nullptr; ga.Cf = nullptr; ga.Ch = qctx; ga.ldc = 1024; ga.sCz = (long long)512 * 1024; ga.K = 512;
  gemm_tn<<<dim3(16, 8, 64), 256, 0, stream>>>(ga);

  float* out_attn = (float*)d_out + (size_t)Bb * D2H;
  gf_fused<<<dim3(32, 512), 256, 0, stream>>>(qctx, allh, wgf, b_g, b_f, out_attn);

  write_concat<<<(Bb * D2H + 255) / 256, 256, 0, stream>>>(h1fin, (float*)d_out);
}

// Round 4
// 7268.095 us; speedup vs baseline: 2.1909x; 1.7073x over previous
//
#include <hip/hip_runtime.h>
#include <hip/hip_bf16.h>
#include <math.h>

typedef _Float16 f16x8 __attribute__((ext_vector_type(8)));
typedef float    f32x4 __attribute__((ext_vector_type(4)));

#define DEV __device__ __forceinline__

static constexpr int Ee   = 300;   // glove dim
static constexpr int INP  = 303;   // E + 3
static constexpr int INPP = 320;   // padded input dim
static constexpr int Hh   = 512;
static constexpr int Bb   = 64;
static constexpr int Tt   = 512;
static constexpr int D2H  = 1024;  // 2H
static constexpr int SLAB = Bb * Hh;  // one h-state slab (elements)

typedef const void __attribute__((address_space(1)))* gas_t;
typedef void __attribute__((address_space(3)))* las_t;

// ---- MFMA fragment load: K-major matrix M[row][k], frag[l][j] = M[row0+(l&15)][k0+8*(l>>4)+j]
DEV f16x8 ldfrag(const _Float16* base, int ld, int row0, int k0, int lane) {
  return *reinterpret_cast<const f16x8*>(base + (size_t)(row0 + (lane & 15)) * ld + (k0 + 8 * (lane >> 4)));
}
DEV float sigm(float x) { return 1.0f / (1.0f + expf(-x)); }

// ---------------- weight convert (f32 -> f16, optional column pad) ----------------
__global__ void convert_pad(const float* __restrict__ src, _Float16* __restrict__ dst,
                            int rows, int csrc, int cdst) {
  int i = blockIdx.x * 256 + threadIdx.x;
  if (i >= rows * cdst) return;
  int r = i / cdst, c = i - r * cdst;
  dst[i] = (c < csrc) ? (_Float16)src[(size_t)r * csrc + c] : (_Float16)0.0f;
}

// ---------------- embedding: xt (T, B, INPP) f16 ----------------
__global__ void embed_kernel(const int* __restrict__ context, const int* __restrict__ tags,
                             const float* __restrict__ glove, const float* __restrict__ bio,
                             _Float16* __restrict__ xt) {
  int blk = blockIdx.x;            // t*64 + b
  int t = blk >> 6, b = blk & 63;
  int cid = context[b * Tt + t];   // context (B,T,1)
  int tag = tags[b * Tt + t];      // (B,T)
  _Float16* dst = xt + (size_t)blk * INPP;
  for (int c = threadIdx.x; c < INPP; c += 64) {
    float v = (c < Ee) ? glove[(size_t)cid * Ee + c]
                       : ((c < INP) ? bio[tag * 3 + (c - Ee)] : 0.0f);
    dst[c] = (_Float16)v;
  }
}

// ---------------- persistent GRU recurrence ----------------
// unit = layer*2 + dir. hb slabs: hb + ((size_t)t*4 + unit)*SLAB holds h_{t-1}
// (slab t=0 zeros). Step t reads slab t, write-through publishes slab t+1.
struct GruParams {
  const _Float16* xt;
  const _Float16* Wx[4];   // input-side weights (ld = 320 for L1, 512 for L2)
  const _Float16* Wh[4];   // hidden-side weights (ld = 512)
  const float* bih[4];
  const float* bhh[4];
  _Float16* hb;            // fresh h16 slabs, (Tt+1) x 4 x SLAB
  _Float16* allh;          // (B, T, 2H) f16
  float*    h1fin;         // [dir][64][512] fp32 layer-1 final states
};

// stage a 64KB slab (64x512 f16) into LDS, linear dest, inverse-swizzled source.
// read-side applies the same XOR -> conflict-free(2-way) ds_read_b128.
DEV void stage64k(const char* __restrict__ gsrc, char* lbase, int tid) {
#pragma unroll
  for (int it = 0; it < 16; ++it) {
    int o = (it * 256 + tid) * 16;
    int row = o >> 10, boff = o & 1023;
    int srcOff = (row << 10) | (boff ^ ((row & 7) << 4));
    __builtin_amdgcn_global_load_lds((gas_t)(gsrc + srcOff), (las_t)(lbase + o), 16, 0, 0);
  }
}

// A-fragment read from a staged+swizzled 64x512 f16 LDS slab
DEV f16x8 ldsfrag(const char* lbase, int mt, int k0, int lane) {
  int row = mt * 16 + (lane & 15);
  int b = (k0 + 8 * (lane >> 4)) * 2;
  int addr = (row << 10) + (b ^ ((row & 7) << 4));
  return *reinterpret_cast<const f16x8*>(lbase + addr);
}

__global__ __launch_bounds__(256, 1) void gru_persist(GruParams P, unsigned* flags) {
  int unit = blockIdx.x >> 5;         // layer*2 + dir
  int blk  = blockIdx.x & 31;
  int cb   = blk << 4;                // h-column base
  int layer = unit >> 1, dir = unit & 1;
  unsigned* myFlag = flags + ((size_t)unit * 32 + blk) * 16;  // 64B/flag
  const unsigned* ownF = flags + (size_t)unit * 32 * 16;
  const unsigned* l1F  = flags + (size_t)dir  * 32 * 16;      // L1 unit of same dir

  int tid = threadIdx.x;
  int w = tid >> 6, lane = tid & 63;
  // wave roles: 0 -> r, 1 -> z, 2 -> n_i (x-side only), 3 -> n_h (h-side only)
  int nrow = ((w == 0) ? 0 : (w == 1) ? Hh : 2 * Hh) + cb;

  const _Float16* Wx = P.Wx[unit];
  const _Float16* Wh = P.Wh[unit];
  const float* bih = P.bih[unit];
  const float* bhh = P.bhh[unit];

  int col = lane & 15;
  float bv;
  if      (w == 0) bv = bih[cb + col] + bhh[cb + col];
  else if (w == 1) bv = bih[Hh + cb + col] + bhh[Hh + cb + col];
  else if (w == 2) bv = bih[2 * Hh + cb + col];
  else             bv = bhh[2 * Hh + cb + col];

  __shared__ _Float16 ldsH[SLAB];     // 64KB staged hprev
  __shared__ _Float16 ldsX[SLAB];     // 64KB staged h1 (L2 only)
  __shared__ float gl[4][64][20];     // gate pre-activations (stride 20: 2-way banks)
  __shared__ float h32s[64][17];      // block-private fp32 h state
  for (int e = tid; e < 64 * 17; e += 256) ((float*)h32s)[e] = 0.0f;
  __syncthreads();

  int rbase = 4 * (lane >> 4);
  int erow = tid >> 2, ec0 = (tid & 3) << 2;  // epilogue: 4 cols/thread

  if (layer == 0) {
    // ---- preload weights into registers (static full-unroll indexing) ----
    f16x8 wxr[10], whr[16];
    if (w != 3) {
#pragma unroll
      for (int k = 0; k < 10; ++k) wxr[k] = ldfrag(Wx, INPP, nrow, k * 32, lane);
    }
    if (w != 2) {
#pragma unroll
      for (int k = 0; k < 16; ++k) whr[k] = ldfrag(Wh, Hh, nrow, k * 32, lane);
    }
    for (int t = 0; t < Tt; ++t) {
      f32x4 acc[4] = {{0.f,0.f,0.f,0.f},{0.f,0.f,0.f,0.f},{0.f,0.f,0.f,0.f},{0.f,0.f,0.f,0.f}};
      // x-side first: independent of the barrier, hides x-tile latency
      if (w != 3) {
        int tt = dir ? (Tt - 1 - t) : t;
        const _Float16* arow = P.xt + (size_t)tt * Bb * INPP + (lane & 15) * INPP + 8 * (lane >> 4);
#pragma unroll
        for (int k = 0; k < 10; ++k)
#pragma unroll
          for (int mt = 0; mt < 4; ++mt)
            acc[mt] = __builtin_amdgcn_mfma_f32_16x16x32_f16(
                *(const f16x8*)(arow + mt * 16 * INPP + k * 32), wxr[k], acc[mt], 0, 0, 0);
      }
      // wait: all 32 sibling blocks published step t-1 (parallel per-flag polls)
      if (tid < 32) {
        const unsigned* p = ownF + tid * 16;
        while (__hip_atomic_load(p, __ATOMIC_RELAXED, __HIP_MEMORY_SCOPE_AGENT) < (unsigned)t)
          __builtin_amdgcn_s_sleep(1);
      }
      __syncthreads();
      stage64k((const char*)(P.hb + ((size_t)t * 4 + unit) * SLAB), (char*)ldsH, tid);
      asm volatile("s_waitcnt vmcnt(0)" ::: "memory");
      __syncthreads();
      if (w != 2) {
#pragma unroll
        for (int k = 0; k < 16; ++k)
#pragma unroll
          for (int mt = 0; mt < 4; ++mt)
            acc[mt] = __builtin_amdgcn_mfma_f32_16x16x32_f16(
                ldsfrag((const char*)ldsH, mt, k * 32, lane), whr[k], acc[mt], 0, 0, 0);
      }
#pragma unroll
      for (int mt = 0; mt < 4; ++mt)
#pragma unroll
        for (int r = 0; r < 4; ++r)
          gl[w][mt * 16 + rbase + r][col] = acc[mt][r] + bv;
      __syncthreads();

      union { _Float16 h[4]; unsigned long long u; } pk;
      float hv[4];
#pragma unroll
      for (int j = 0; j < 4; ++j) {
        int c = ec0 + j;
        float rr = sigm(gl[0][erow][c]);
        float zz = sigm(gl[1][erow][c]);
        float nn = tanhf(gl[2][erow][c] + rr * gl[3][erow][c]);
        float hp = h32s[erow][c];
        hv[j] = (1.0f - zz) * nn + zz * hp;
        h32s[erow][c] = hv[j];
        pk.h[j] = (_Float16)hv[j];
      }
      _Float16* hout = P.hb + ((size_t)(t + 1) * 4 + unit) * SLAB + erow * Hh + cb + ec0;
      __hip_atomic_store((unsigned long long*)hout, pk.u, __ATOMIC_RELAXED, __HIP_MEMORY_SCOPE_AGENT);
      if (t == Tt - 1)
        *(float4*)(P.h1fin + ((size_t)dir * Bb + erow) * Hh + cb + ec0) = make_float4(hv[0], hv[1], hv[2], hv[3]);

      asm volatile("s_waitcnt vmcnt(0)" ::: "memory");
      __syncthreads();
      if (tid == 0)
        __hip_atomic_store(myFlag, (unsigned)(t + 1), __ATOMIC_RELAXED, __HIP_MEMORY_SCOPE_AGENT);
    }
  } else {
    f16x8 wxr[16], whr[16];
    if (w != 3) {
#pragma unroll
      for (int k = 0; k < 16; ++k) wxr[k] = ldfrag(Wx, Hh, nrow, k * 32, lane);
    }
    if (w != 2) {
#pragma unroll
      for (int k = 0; k < 16; ++k) whr[k] = ldfrag(Wh, Hh, nrow, k * 32, lane);
    }
    for (int t = 0; t < Tt; ++t) {
      // wait: own siblings >= t AND producing L1 unit >= t+1 (h1(t) complete)
      if (tid < 64) {
        const unsigned* p = (tid < 32) ? (ownF + tid * 16) : (l1F + (tid - 32) * 16);
        unsigned tg = (tid < 32) ? (unsigned)t : (unsigned)(t + 1);
        while (__hip_atomic_load(p, __ATOMIC_RELAXED, __HIP_MEMORY_SCOPE_AGENT) < tg)
          __builtin_amdgcn_s_sleep(1);
      }
      __syncthreads();
      stage64k((const char*)(P.hb + ((size_t)(t + 1) * 4 + dir) * SLAB), (char*)ldsX, tid);  // h1(t)
      stage64k((const char*)(P.hb + ((size_t)t * 4 + unit) * SLAB),     (char*)ldsH, tid);   // own hprev
      asm volatile("s_waitcnt vmcnt(0)" ::: "memory");
      __syncthreads();

      f32x4 acc[4] = {{0.f,0.f,0.f,0.f},{0.f,0.f,0.f,0.f},{0.f,0.f,0.f,0.f},{0.f,0.f,0.f,0.f}};
      if (w != 3) {
#pragma unroll
        for (int k = 0; k < 16; ++k)
#pragma unroll
          for (int mt = 0; mt < 4; ++mt)
            acc[mt] = __builtin_amdgcn_mfma_f32_16x16x32_f16(
                ldsfrag((const char*)ldsX, mt, k * 32, lane), wxr[k], acc[mt], 0, 0, 0);
      }
      if (w != 2) {
#pragma unroll
        for (int k = 0; k < 16; ++k)
#pragma unroll
          for (int mt = 0; mt < 4; ++mt)
            acc[mt] = __builtin_amdgcn_mfma_f32_16x16x32_f16(
                ldsfrag((const char*)ldsH, mt, k * 32, lane), whr[k], acc[mt], 0, 0, 0);
      }
#pragma unroll
      for (int mt = 0; mt < 4; ++mt)
#pragma unroll
        for (int r = 0; r < 4; ++r)
          gl[w][mt * 16 + rbase + r][col] = acc[mt][r] + bv;
      __syncthreads();

      union { _Float16 h[4]; unsigned long long u; } pk;
      float hv[4];
#pragma unroll
      for (int j = 0; j < 4; ++j) {
        int c = ec0 + j;
        float rr = sigm(gl[0][erow][c]);
        float zz = sigm(gl[1][erow][c]);
        float nn = tanhf(gl[2][erow][c] + rr * gl[3][erow][c]);
        float hp = h32s[erow][c];
        hv[j] = (1.0f - zz) * nn + zz * hp;
        h32s[erow][c] = hv[j];
        pk.h[j] = (_Float16)hv[j];
      }
      _Float16* hout = P.hb + ((size_t)(t + 1) * 4 + unit) * SLAB + erow * Hh + cb + ec0;
      __hip_atomic_store((unsigned long long*)hout, pk.u, __ATOMIC_RELAXED, __HIP_MEMORY_SCOPE_AGENT);
      *(unsigned long long*)(P.allh + ((size_t)erow * Tt + t) * D2H + dir * Hh + cb + ec0) = pk.u;

      asm volatile("s_waitcnt vmcnt(0)" ::: "memory");
      __syncthreads();
      if (tid == 0)
        __hip_atomic_store(myFlag, (unsigned)(t + 1), __ATOMIC_RELAXED, __HIP_MEMORY_SCOPE_AGENT);
    }
  }
}

// ---------------- generic TN GEMM: C = A(MxK) * B(NxK)^T (+bias) ----------------
struct GemmArgs {
  const _Float16* A; const _Float16* Bm;
  float* Cf; _Float16* Ch;
  const float* bias;
  int lda, ldb, ldc, K;
  long long sAz, sBz, sCz;
};

__global__ __launch_bounds__(256) void gemm_tn(GemmArgs g) {
  int z = blockIdx.z;
  const _Float16* A  = g.A  + (size_t)z * g.sAz;
  const _Float16* Bm = g.Bm + (size_t)z * g.sBz;
  int m0 = blockIdx.y * 64;
  int lane = threadIdx.x & 63;
  int n0 = blockIdx.x * 64 + (threadIdx.x >> 6) * 16;

  f32x4 a0 = {0.f,0.f,0.f,0.f}, a1 = a0, a2 = a0, a3 = a0;
  for (int k0 = 0; k0 < g.K; k0 += 32) {
    f16x8 bfr = ldfrag(Bm, g.ldb, n0, k0, lane);
    a0 = __builtin_amdgcn_mfma_f32_16x16x32_f16(ldfrag(A, g.lda, m0 +  0, k0, lane), bfr, a0, 0,0,0);
    a1 = __builtin_amdgcn_mfma_f32_16x16x32_f16(ldfrag(A, g.lda, m0 + 16, k0, lane), bfr, a1, 0,0,0);
    a2 = __builtin_amdgcn_mfma_f32_16x16x32_f16(ldfrag(A, g.lda, m0 + 32, k0, lane), bfr, a2, 0,0,0);
    a3 = __builtin_amdgcn_mfma_f32_16x16x32_f16(ldfrag(A, g.lda, m0 + 48, k0, lane), bfr, a3, 0,0,0);
  }
  int col = n0 + (lane & 15);
  float bv = g.bias ? g.bias[col] : 0.0f;
  int rbase = 4 * (lane >> 4);
  f32x4 acc[4] = {a0, a1, a2, a3};
#pragma unroll
  for (int mt = 0; mt < 4; ++mt)
#pragma unroll
    for (int r = 0; r < 4; ++r) {
      int row = m0 + mt * 16 + rbase + r;
      float v = acc[mt][r] + bv;
      size_t idx = (size_t)z * g.sCz + (size_t)row * g.ldc + col;
      if (g.Cf) g.Cf[idx] = v; else g.Ch[idx] = (_Float16)v;
    }
}

// ---------------- row softmax: scores f32 (.,512) -> p f16 ----------------
__global__ __launch_bounds__(256) void softmax_rows(const float* __restrict__ sc, _Float16* __restrict__ p) {
  int row = blockIdx.x * 4 + (threadIdx.x >> 6);
  int lane = threadIdx.x & 63;
  const float* s = sc + (size_t)row * 512 + lane * 8;
  float v[8];
  float4 q0 = *(const float4*)s, q1 = *(const float4*)(s + 4);
  v[0]=q0.x; v[1]=q0.y; v[2]=q0.z; v[3]=q0.w; v[4]=q1.x; v[5]=q1.y; v[6]=q1.z; v[7]=q1.w;
  float mx = v[0];
#pragma unroll
  for (int j = 1; j < 8; ++j) mx = fmaxf(mx, v[j]);
  for (int o = 32; o; o >>= 1) mx = fmaxf(mx, __shfl_xor(mx, o));
  float sum = 0.f;
#pragma unroll
  for (int j = 0; j < 8; ++j) { v[j] = expf(v[j] - mx); sum += v[j]; }
  for (int o = 32; o; o >>= 1) sum += __shfl_xor(sum, o);
  float inv = 1.0f / sum;
  _Float16* pd = p + (size_t)row * 512 + lane * 8;
#pragma unroll
  for (int j = 0; j < 8; ++j) pd[j] = (_Float16)(v[j] * inv);
}

// ---------------- per-batch transpose: allhT[b][d][t] = allh[b][t][d] ----------------
__global__ void transpose_bt(const _Float16* __restrict__ allh, _Float16* __restrict__ allhT) {
  __shared__ _Float16 tile[32][33];
  int b = blockIdx.z;
  int d0 = blockIdx.x * 32, t0 = blockIdx.y * 32;
  int tx = threadIdx.x, ty = threadIdx.y;  // (32, 8)
  const _Float16* in = allh + (size_t)b * Tt * D2H;
  _Float16* outp = allhT + (size_t)b * D2H * Tt;
#pragma unroll
  for (int j = 0; j < 4; ++j)
    tile[ty + 8 * j][tx] = in[(size_t)(t0 + ty + 8 * j) * D2H + d0 + tx];
  __syncthreads();
#pragma unroll
  for (int j = 0; j < 4; ++j)
    outp[(size_t)(d0 + ty + 8 * j) * Tt + t0 + tx] = tile[tx][ty + 8 * j];
}

// ---------------- fused g/f GEMM + gating epilogue -> attn (f32) ----------------
__global__ __launch_bounds__(256) void gf_fused(const _Float16* __restrict__ ctx,
                                                const _Float16* __restrict__ allh,
                                                const _Float16* __restrict__ Wgf,
                                                const float* __restrict__ bg,
                                                const float* __restrict__ bfv,
                                                float* __restrict__ out_attn) {
  int m0 = blockIdx.y * 64;
  int cb = blockIdx.x * 32;
  int w = threadIdx.x >> 6, lane = threadIdx.x & 63;
  int nrow = (w >> 1) * 1024 + cb + (w & 1) * 16;  // w0,w1: g cols; w2,w3: f cols

  f32x4 a0 = {0.f,0.f,0.f,0.f}, a1 = a0, a2 = a0, a3 = a0;
  for (int k0 = 0; k0 < 1024; k0 += 32) {   // phase 1: cat[:,0:1024] = ctx
    f16x8 bfr = ldfrag(Wgf, 2048, nrow, k0, lane);
    a0 = __builtin_amdgcn_mfma_f32_16x16x32_f16(ldfrag(ctx, 1024, m0 +  0, k0, lane), bfr, a0, 0,0,0);
    a1 = __builtin_amdgcn_mfma_f32_16x16x32_f16(ldfrag(ctx, 1024, m0 + 16, k0, lane), bfr, a1, 0,0,0);
    a2 = __builtin_amdgcn_mfma_f32_16x16x32_f16(ldfrag(ctx, 1024, m0 + 32, k0, lane), bfr, a2, 0,0,0);
    a3 = __builtin_amdgcn_mfma_f32_16x16x32_f16(ldfrag(ctx, 1024, m0 + 48, k0, lane), bfr, a3, 0,0,0);
  }
  for (int k0 = 0; k0 < 1024; k0 += 32) {   // phase 2: cat[:,1024:2048] = all_h
    f16x8 bfr = ldfrag(Wgf, 2048, nrow, 1024 + k0, lane);
    a0 = __builtin_amdgcn_mfma_f32_16x16x32_f16(ldfrag(allh, 1024, m0 +  0, k0, lane), bfr, a0, 0,0,0);
    a1 = __builtin_amdgcn_mfma_f32_16x16x32_f16(ldfrag(allh, 1024, m0 + 16, k0, lane), bfr, a1, 0,0,0);
    a2 = __builtin_amdgcn_mfma_f32_16x16x32_f16(ldfrag(allh, 1024, m0 + 32, k0, lane), bfr, a2, 0,0,0);
    a3 = __builtin_amdgcn_mfma_f32_16x16x32_f16(ldfrag(allh, 1024, m0 + 48, k0, lane), bfr, a3, 0,0,0);
  }
  int col = lane & 15;
  int n = nrow + col;
  float bv = (n < 1024) ? bg[n] : bfv[n - 1024];

  __shared__ float lds[4][64][16];
  int rbase = 4 * (lane >> 4);
  f32x4 acc[4] = {a0, a1, a2, a3};
#pragma unroll
  for (int mt = 0; mt < 4; ++mt)
#pragma unroll
    for (int r = 0; r < 4; ++r)
      lds[w][mt * 16 + rbase + r][col] = acc[mt][r] + bv;
  __syncthreads();

  for (int e = threadIdx.x; e < 64 * 32; e += 256) {
    int row = e >> 5, c = e & 31;
    float gv = lds[c >> 4][row][c & 15];
    float fv = lds[2 + (c >> 4)][row][c & 15];
    float gg = sigm(gv);
    float ff = tanhf(fv);
    int m = m0 + row, cg = cb + c;
    float ah = (float)allh[(size_t)m * D2H + cg];
    out_attn[(size_t)m * D2H + cg] = gg * ff + (1.0f - gg) * ah;
  }
}

// ---------------- final concat output ----------------
__global__ void write_concat(const float* __restrict__ h1fin, float* __restrict__ out) {
  int i = blockIdx.x * 256 + threadIdx.x;
  if (i >= Bb * D2H) return;
  int b = i >> 10, c = i & 1023;
  out[i] = (c < Hh) ? h1fin[(size_t)b * Hh + c] : h1fin[(size_t)(Bb + b) * Hh + (c - Hh)];
}

// =============================== host ===============================
extern "C" void kernel_launch(void* const* d_in, const int* in_sizes, int n_in,
                              void* d_out, int out_size, void* d_ws, size_t ws_size,
                              hipStream_t stream) {
  const int*   context = (const int*)d_in[0];
  const int*   tags    = (const int*)d_in[1];
  const float* glove   = (const float*)d_in[2];
  const float* bio     = (const float*)d_in[3];
  const float* b_lin   = (const float*)d_in[21];
  const float* b_g     = (const float*)d_in[23];
  const float* b_f     = (const float*)d_in[25];

  char* ws = (char*)d_ws;
  size_t off = 0;
  auto carve = [&](size_t bytes) -> void* {
    void* pp = ws + off;
    off = (off + bytes + 255) & ~(size_t)255;
    return pp;
  };

  _Float16* xt = (_Float16*)carve((size_t)Tt * Bb * INPP * 2);
  _Float16 *Wx16[2][2], *Wh16[2][2];
  Wx16[0][0] = (_Float16*)carve((size_t)1536 * 320 * 2);
  Wx16[1][0] = (_Float16*)carve((size_t)1536 * 320 * 2);
  Wx16[0][1] = (_Float16*)carve((size_t)1536 * 512 * 2);
  Wx16[1][1] = (_Float16*)carve((size_t)1536 * 512 * 2);
  for (int d = 0; d < 2; ++d)
    for (int l = 0; l < 2; ++l) Wh16[d][l] = (_Float16*)carve((size_t)1536 * 512 * 2);
  _Float16* wlin = (_Float16*)carve((size_t)1024 * 1024 * 2);
  _Float16* wgf  = (_Float16*)carve((size_t)2048 * 2048 * 2);
  _Float16* allh  = (_Float16*)carve((size_t)Bb * Tt * D2H * 2);
  _Float16* allhT = (_Float16*)carve((size_t)Bb * Tt * D2H * 2);   // also hosts hb during recurrence
  _Float16* qctx  = (_Float16*)carve((size_t)Bb * Tt * D2H * 2);   // q, then reused as ctx
  float*    scores = (float*)carve((size_t)Bb * Tt * Tt * 4);
  _Float16* pmat   = (_Float16*)carve((size_t)Bb * Tt * Tt * 2);
  float*    h1fin  = (float*)carve((size_t)2 * Bb * Hh * 4);
  unsigned* flags  = (unsigned*)carve((size_t)4 * 32 * 16 * 4);    // 8KB, 64B per block-flag

  // hb (fresh h16 slabs) aliases the post-recurrence region [allhT ...]:
  // needs (Tt+1)*4*SLAB*2 = 134.5 MB; allhT+qctx+scores spans ~200 MB. Lifetimes disjoint.
  _Float16* hb = allhT;

  hipMemsetAsync(hb, 0, (size_t)4 * SLAB * 2, stream);          // slab t=0 (4 units) = 0
  hipMemsetAsync(flags, 0, (size_t)4 * 32 * 16 * 4, stream);    // progress flags

  auto conv = [&](const void* src, _Float16* dst, int rows, int csrc, int cdst) {
    int total = rows * cdst;
    convert_pad<<<(total + 255) / 256, 256, 0, stream>>>((const float*)src, dst, rows, csrc, cdst);
  };
  conv(d_in[4],  Wx16[0][0], 1536, 303, 320);
  conv(d_in[12], Wx16[1][0], 1536, 303, 320);
  conv(d_in[8],  Wx16[0][1], 1536, 512, 512);
  conv(d_in[16], Wx16[1][1], 1536, 512, 512);
  conv(d_in[5],  Wh16[0][0], 1536, 512, 512);
  conv(d_in[13], Wh16[1][0], 1536, 512, 512);
  conv(d_in[9],  Wh16[0][1], 1536, 512, 512);
  conv(d_in[17], Wh16[1][1], 1536, 512, 512);
  conv(d_in[20], wlin, 1024, 1024, 1024);
  conv(d_in[22], wgf, 1024, 2048, 2048);
  conv(d_in[24], wgf + (size_t)1024 * 2048, 1024, 2048, 2048);

  embed_kernel<<<Tt * Bb, 64, 0, stream>>>(context, tags, glove, bio, xt);

  GruParams GP;
  GP.xt = xt;
  // unit = layer*2 + dir
  GP.Wx[0] = Wx16[0][0]; GP.Wx[1] = Wx16[1][0]; GP.Wx[2] = Wx16[0][1]; GP.Wx[3] = Wx16[1][1];
  GP.Wh[0] = Wh16[0][0]; GP.Wh[1] = Wh16[1][0]; GP.Wh[2] = Wh16[0][1]; GP.Wh[3] = Wh16[1][1];
  GP.bih[0] = (const float*)d_in[6];  GP.bhh[0] = (const float*)d_in[7];
  GP.bih[1] = (const float*)d_in[14]; GP.bhh[1] = (const float*)d_in[15];
  GP.bih[2] = (const float*)d_in[10]; GP.bhh[2] = (const float*)d_in[11];
  GP.bih[3] = (const float*)d_in[18]; GP.bhh[3] = (const float*)d_in[19];
  GP.hb = hb;
  GP.allh = allh;
  GP.h1fin = h1fin;

  gru_persist<<<128, 256, 0, stream>>>(GP, flags);

  // q = all_h @ W_lin^T + b_lin  -> f16
  GemmArgs ga;
  ga.A = allh; ga.lda = 1024; ga.sAz = 0;
  ga.Bm = wlin; ga.ldb = 1024; ga.sBz = 0;
  ga.bias = b_lin; ga.Cf = nullptr; ga.Ch = qctx; ga.ldc = 1024; ga.sCz = 0; ga.K = 1024;
  gemm_tn<<<dim3(16, 512, 1), 256, 0, stream>>>(ga);

  // scores[b] = q[b] @ all_h[b]^T -> f32
  ga.A = qctx; ga.lda = 1024; ga.sAz = (long long)512 * 1024;
  ga.Bm = allh; ga.ldb = 1024; ga.sBz = (long long)512 * 1024;
  ga.bias = nullptr; ga.Cf = scores; ga.Ch = nullptr; ga.ldc = 512; ga.sCz = (long long)512 * 512; ga.K = 1024;
  gemm_tn<<<dim3(8, 8, 64), 256, 0, stream>>>(ga);

  softmax_rows<<<(Bb * Tt) / 4, 256, 0, stream>>>(scores, pmat);

  transpose_bt<<<dim3(32, 16, 64), dim3(32, 8), 0, stream>>>(allh, allhT);

  // ctx[b] = p[b] @ (all_hT[b])^T  -> f16 (overwrites q)
  ga.A = pmat; ga.lda = 512; ga.sAz = (long long)512 * 512;
  ga.Bm = allhT; ga.ldb = 512; ga.sBz = (long long)1024 * 512;
  ga.bias = nullptr; ga.Cf = nullptr; ga.Ch = qctx; ga.ldc = 1024; ga.sCz = (long long)512 * 1024; ga.K = 512;
  gemm_tn<<<dim3(16, 8, 64), 256, 0, stream>>>(ga);

  float* out_attn = (float*)d_out + (size_t)Bb * D2H;
  gf_fused<<<dim3(32, 512), 256, 0, stream>>>(qctx, allh, wgf, b_g, b_f, out_attn);

  write_concat<<<(Bb * D2H + 255) / 256, 256, 0, stream>>>(h1fin, (float*)d_out);
}

// Round 5
// 4548.036 us; speedup vs baseline: 3.5013x; 1.5981x over previous
//
#include <hip/hip_runtime.h>
#include <hip/hip_bf16.h>
#include <math.h>

typedef _Float16 f16x8 __attribute__((ext_vector_type(8)));
typedef float    f32x4 __attribute__((ext_vector_type(4)));

#define DEV __device__ __forceinline__

static constexpr int Ee   = 300;   // glove dim
static constexpr int INP  = 303;   // E + 3
static constexpr int INPP = 320;   // padded input dim
static constexpr int Hh   = 512;
static constexpr int Bb   = 64;
static constexpr int Tt   = 512;
static constexpr int D2H  = 1024;  // 2H
static constexpr int SLAB = Bb * Hh;  // one h-state slab (elements)

typedef const void __attribute__((address_space(1)))* gas_t;
typedef void __attribute__((address_space(3)))* las_t;

// ---- MFMA fragment load: K-major matrix M[row][k], frag[l][j] = M[row0+(l&15)][k0+8*(l>>4)+j]
DEV f16x8 ldfrag(const _Float16* base, int ld, int row0, int k0, int lane) {
  return *reinterpret_cast<const f16x8*>(base + (size_t)(row0 + (lane & 15)) * ld + (k0 + 8 * (lane >> 4)));
}
DEV float sigm(float x) { return 1.0f / (1.0f + expf(-x)); }

// ---------------- weight convert (f32 -> f16, optional column pad) ----------------
__global__ void convert_pad(const float* __restrict__ src, _Float16* __restrict__ dst,
                            int rows, int csrc, int cdst) {
  int i = blockIdx.x * 256 + threadIdx.x;
  if (i >= rows * cdst) return;
  int r = i / cdst, c = i - r * cdst;
  dst[i] = (c < csrc) ? (_Float16)src[(size_t)r * csrc + c] : (_Float16)0.0f;
}

// ---------------- embedding: xt (T, B, INPP) f16 ----------------
__global__ void embed_kernel(const int* __restrict__ context, const int* __restrict__ tags,
                             const float* __restrict__ glove, const float* __restrict__ bio,
                             _Float16* __restrict__ xt) {
  int blk = blockIdx.x;            // t*64 + b
  int t = blk >> 6, b = blk & 63;
  int cid = context[b * Tt + t];   // context (B,T,1)
  int tag = tags[b * Tt + t];      // (B,T)
  _Float16* dst = xt + (size_t)blk * INPP;
  for (int c = threadIdx.x; c < INPP; c += 64) {
    float v = (c < Ee) ? glove[(size_t)cid * Ee + c]
                       : ((c < INP) ? bio[tag * 3 + (c - Ee)] : 0.0f);
    dst[c] = (_Float16)v;
  }
}

// ---------------- persistent GRU recurrence (unchanged from round 4) ----------------
struct GruParams {
  const _Float16* xt;
  const _Float16* Wx[4];   // input-side weights (ld = 320 for L1, 512 for L2)
  const _Float16* Wh[4];   // hidden-side weights (ld = 512)
  const float* bih[4];
  const float* bhh[4];
  _Float16* hb;            // fresh h16 slabs, (Tt+1) x 4 x SLAB
  _Float16* allh;          // (B, T, 2H) f16
  float*    h1fin;         // [dir][64][512] fp32 layer-1 final states
};

// stage a 64KB slab (64x512 f16) into LDS, linear dest, inverse-swizzled source.
DEV void stage64k(const char* __restrict__ gsrc, char* lbase, int tid) {
#pragma unroll
  for (int it = 0; it < 16; ++it) {
    int o = (it * 256 + tid) * 16;
    int row = o >> 10, boff = o & 1023;
    int srcOff = (row << 10) | (boff ^ ((row & 7) << 4));
    __builtin_amdgcn_global_load_lds((gas_t)(gsrc + srcOff), (las_t)(lbase + o), 16, 0, 0);
  }
}

// A-fragment read from a staged+swizzled 64x512 f16 LDS slab
DEV f16x8 ldsfrag(const char* lbase, int mt, int k0, int lane) {
  int row = mt * 16 + (lane & 15);
  int b = (k0 + 8 * (lane >> 4)) * 2;
  int addr = (row << 10) + (b ^ ((row & 7) << 4));
  return *reinterpret_cast<const f16x8*>(lbase + addr);
}

__global__ __launch_bounds__(256, 1) void gru_persist(GruParams P, unsigned* flags) {
  int unit = blockIdx.x >> 5;         // layer*2 + dir
  int blk  = blockIdx.x & 31;
  int cb   = blk << 4;                // h-column base
  int layer = unit >> 1, dir = unit & 1;
  unsigned* myFlag = flags + ((size_t)unit * 32 + blk) * 16;  // 64B/flag
  const unsigned* ownF = flags + (size_t)unit * 32 * 16;
  const unsigned* l1F  = flags + (size_t)dir  * 32 * 16;      // L1 unit of same dir

  int tid = threadIdx.x;
  int w = tid >> 6, lane = tid & 63;
  int nrow = ((w == 0) ? 0 : (w == 1) ? Hh : 2 * Hh) + cb;

  const _Float16* Wx = P.Wx[unit];
  const _Float16* Wh = P.Wh[unit];
  const float* bih = P.bih[unit];
  const float* bhh = P.bhh[unit];

  int col = lane & 15;
  float bv;
  if      (w == 0) bv = bih[cb + col] + bhh[cb + col];
  else if (w == 1) bv = bih[Hh + cb + col] + bhh[Hh + cb + col];
  else if (w == 2) bv = bih[2 * Hh + cb + col];
  else             bv = bhh[2 * Hh + cb + col];

  __shared__ _Float16 ldsH[SLAB];     // 64KB staged hprev
  __shared__ _Float16 ldsX[SLAB];     // 64KB staged h1 (L2 only)
  __shared__ float gl[4][64][20];     // gate pre-activations
  __shared__ float h32s[64][17];      // block-private fp32 h state
  for (int e = tid; e < 64 * 17; e += 256) ((float*)h32s)[e] = 0.0f;
  __syncthreads();

  int rbase = 4 * (lane >> 4);
  int erow = tid >> 2, ec0 = (tid & 3) << 2;

  if (layer == 0) {
    f16x8 wxr[10], whr[16];
    if (w != 3) {
#pragma unroll
      for (int k = 0; k < 10; ++k) wxr[k] = ldfrag(Wx, INPP, nrow, k * 32, lane);
    }
    if (w != 2) {
#pragma unroll
      for (int k = 0; k < 16; ++k) whr[k] = ldfrag(Wh, Hh, nrow, k * 32, lane);
    }
    for (int t = 0; t < Tt; ++t) {
      f32x4 acc[4] = {{0.f,0.f,0.f,0.f},{0.f,0.f,0.f,0.f},{0.f,0.f,0.f,0.f},{0.f,0.f,0.f,0.f}};
      if (w != 3) {
        int tt = dir ? (Tt - 1 - t) : t;
        const _Float16* arow = P.xt + (size_t)tt * Bb * INPP + (lane & 15) * INPP + 8 * (lane >> 4);
#pragma unroll
        for (int k = 0; k < 10; ++k)
#pragma unroll
          for (int mt = 0; mt < 4; ++mt)
            acc[mt] = __builtin_amdgcn_mfma_f32_16x16x32_f16(
                *(const f16x8*)(arow + mt * 16 * INPP + k * 32), wxr[k], acc[mt], 0, 0, 0);
      }
      if (tid < 32) {
        const unsigned* p = ownF + tid * 16;
        while (__hip_atomic_load(p, __ATOMIC_RELAXED, __HIP_MEMORY_SCOPE_AGENT) < (unsigned)t)
          __builtin_amdgcn_s_sleep(1);
      }
      __syncthreads();
      stage64k((const char*)(P.hb + ((size_t)t * 4 + unit) * SLAB), (char*)ldsH, tid);
      asm volatile("s_waitcnt vmcnt(0)" ::: "memory");
      __syncthreads();
      if (w != 2) {
#pragma unroll
        for (int k = 0; k < 16; ++k)
#pragma unroll
          for (int mt = 0; mt < 4; ++mt)
            acc[mt] = __builtin_amdgcn_mfma_f32_16x16x32_f16(
                ldsfrag((const char*)ldsH, mt, k * 32, lane), whr[k], acc[mt], 0, 0, 0);
      }
#pragma unroll
      for (int mt = 0; mt < 4; ++mt)
#pragma unroll
        for (int r = 0; r < 4; ++r)
          gl[w][mt * 16 + rbase + r][col] = acc[mt][r] + bv;
      __syncthreads();

      union { _Float16 h[4]; unsigned long long u; } pk;
      float hv[4];
#pragma unroll
      for (int j = 0; j < 4; ++j) {
        int c = ec0 + j;
        float rr = sigm(gl[0][erow][c]);
        float zz = sigm(gl[1][erow][c]);
        float nn = tanhf(gl[2][erow][c] + rr * gl[3][erow][c]);
        float hp = h32s[erow][c];
        hv[j] = (1.0f - zz) * nn + zz * hp;
        h32s[erow][c] = hv[j];
        pk.h[j] = (_Float16)hv[j];
      }
      _Float16* hout = P.hb + ((size_t)(t + 1) * 4 + unit) * SLAB + erow * Hh + cb + ec0;
      __hip_atomic_store((unsigned long long*)hout, pk.u, __ATOMIC_RELAXED, __HIP_MEMORY_SCOPE_AGENT);
      if (t == Tt - 1)
        *(float4*)(P.h1fin + ((size_t)dir * Bb + erow) * Hh + cb + ec0) = make_float4(hv[0], hv[1], hv[2], hv[3]);

      asm volatile("s_waitcnt vmcnt(0)" ::: "memory");
      __syncthreads();
      if (tid == 0)
        __hip_atomic_store(myFlag, (unsigned)(t + 1), __ATOMIC_RELAXED, __HIP_MEMORY_SCOPE_AGENT);
    }
  } else {
    f16x8 wxr[16], whr[16];
    if (w != 3) {
#pragma unroll
      for (int k = 0; k < 16; ++k) wxr[k] = ldfrag(Wx, Hh, nrow, k * 32, lane);
    }
    if (w != 2) {
#pragma unroll
      for (int k = 0; k < 16; ++k) whr[k] = ldfrag(Wh, Hh, nrow, k * 32, lane);
    }
    for (int t = 0; t < Tt; ++t) {
      if (tid < 64) {
        const unsigned* p = (tid < 32) ? (ownF + tid * 16) : (l1F + (tid - 32) * 16);
        unsigned tg = (tid < 32) ? (unsigned)t : (unsigned)(t + 1);
        while (__hip_atomic_load(p, __ATOMIC_RELAXED, __HIP_MEMORY_SCOPE_AGENT) < tg)
          __builtin_amdgcn_s_sleep(1);
      }
      __syncthreads();
      stage64k((const char*)(P.hb + ((size_t)(t + 1) * 4 + dir) * SLAB), (char*)ldsX, tid);  // h1(t)
      stage64k((const char*)(P.hb + ((size_t)t * 4 + unit) * SLAB),     (char*)ldsH, tid);   // own hprev
      asm volatile("s_waitcnt vmcnt(0)" ::: "memory");
      __syncthreads();

      f32x4 acc[4] = {{0.f,0.f,0.f,0.f},{0.f,0.f,0.f,0.f},{0.f,0.f,0.f,0.f},{0.f,0.f,0.f,0.f}};
      if (w != 3) {
#pragma unroll
        for (int k = 0; k < 16; ++k)
#pragma unroll
          for (int mt = 0; mt < 4; ++mt)
            acc[mt] = __builtin_amdgcn_mfma_f32_16x16x32_f16(
                ldsfrag((const char*)ldsX, mt, k * 32, lane), wxr[k], acc[mt], 0, 0, 0);
      }
      if (w != 2) {
#pragma unroll
        for (int k = 0; k < 16; ++k)
#pragma unroll
          for (int mt = 0; mt < 4; ++mt)
            acc[mt] = __builtin_amdgcn_mfma_f32_16x16x32_f16(
                ldsfrag((const char*)ldsH, mt, k * 32, lane), whr[k], acc[mt], 0, 0, 0);
      }
#pragma unroll
      for (int mt = 0; mt < 4; ++mt)
#pragma unroll
        for (int r = 0; r < 4; ++r)
          gl[w][mt * 16 + rbase + r][col] = acc[mt][r] + bv;
      __syncthreads();

      union { _Float16 h[4]; unsigned long long u; } pk;
      float hv[4];
#pragma unroll
      for (int j = 0; j < 4; ++j) {
        int c = ec0 + j;
        float rr = sigm(gl[0][erow][c]);
        float zz = sigm(gl[1][erow][c]);
        float nn = tanhf(gl[2][erow][c] + rr * gl[3][erow][c]);
        float hp = h32s[erow][c];
        hv[j] = (1.0f - zz) * nn + zz * hp;
        h32s[erow][c] = hv[j];
        pk.h[j] = (_Float16)hv[j];
      }
      _Float16* hout = P.hb + ((size_t)(t + 1) * 4 + unit) * SLAB + erow * Hh + cb + ec0;
      __hip_atomic_store((unsigned long long*)hout, pk.u, __ATOMIC_RELAXED, __HIP_MEMORY_SCOPE_AGENT);
      *(unsigned long long*)(P.allh + ((size_t)erow * Tt + t) * D2H + dir * Hh + cb + ec0) = pk.u;

      asm volatile("s_waitcnt vmcnt(0)" ::: "memory");
      __syncthreads();
      if (tid == 0)
        __hip_atomic_store(myFlag, (unsigned)(t + 1), __ATOMIC_RELAXED, __HIP_MEMORY_SCOPE_AGENT);
    }
  }
}

// ---------------- tiled TN GEMM: C = [A|A2](MxK, K-major) * B(NxK, K-major)^T ----------------
// 128x128 tile, BK=64, double-buffered global_load_lds staging with XOR swizzle.
struct TArgs {
  const _Float16* A; const _Float16* A2; const _Float16* B;
  _Float16* Ch; float* Cf;
  const float* bias;
  int lda, ldb, ldc, K, Ksplit;
  long long sAz, sBz, sCz;
};

template<int MODE>  // 0: f16 out; 1: f16 out + bias; 2: f32 out
__global__ __launch_bounds__(256) void gemm_tiled(TArgs g) {
  int z = blockIdx.z;
  const _Float16* A  = g.A + (size_t)z * g.sAz;
  const _Float16* Bm = g.B + (size_t)z * g.sBz;
  int m0 = blockIdx.y * 128, n0 = blockIdx.x * 128;
  int tid = threadIdx.x, lane = tid & 63;
  int wr = (tid >> 7) & 1, wc = (tid >> 6) & 1;  // wave grid 2x2

  __shared__ _Float16 sA[2][128 * 64];
  __shared__ _Float16 sB[2][128 * 64];

  int ldab = g.lda * 2, ldbb = g.ldb * 2;

#define STAGE(buf, kt)                                                                   \
  {                                                                                      \
    int k0 = (kt) * 64;                                                                  \
    const _Float16* Asrc = A; int ka = k0;                                               \
    if (k0 >= g.Ksplit) { Asrc = g.A2; ka = k0 - g.Ksplit; }                             \
    const char* ab = (const char*)(Asrc + (size_t)m0 * g.lda + ka);                      \
    const char* bb = (const char*)(Bm  + (size_t)n0 * g.ldb + k0);                       \
    char* la = (char*)sA[buf]; char* lb = (char*)sB[buf];                                \
    _Pragma("unroll")                                                                    \
    for (int it = 0; it < 4; ++it) {                                                     \
      int o = (it * 256 + tid) * 16;                                                     \
      int row = o >> 7, boff = o & 127;                                                  \
      int sw = boff ^ ((row & 7) << 4);                                                  \
      __builtin_amdgcn_global_load_lds((gas_t)(ab + (size_t)row * ldab + sw),            \
                                       (las_t)(la + o), 16, 0, 0);                       \
      __builtin_amdgcn_global_load_lds((gas_t)(bb + (size_t)row * ldbb + sw),            \
                                       (las_t)(lb + o), 16, 0, 0);                       \
    }                                                                                    \
  }

  f32x4 acc[4][4] = {};
  int nkt = g.K / 64;
  STAGE(0, 0);
  asm volatile("s_waitcnt vmcnt(0)" ::: "memory");
  __syncthreads();

  int cbyte = (lane >> 4) << 4;  // 0,16,32,48
  for (int kt = 0; kt < nkt; ++kt) {
    int buf = kt & 1;
    if (kt + 1 < nkt) STAGE(buf ^ 1, kt + 1);
    const char* la = (const char*)sA[buf];
    const char* lb = (const char*)sB[buf];
    f16x8 af[2][4], bfr[2][4];
#pragma unroll
    for (int kk = 0; kk < 2; ++kk) {
#pragma unroll
      for (int mt = 0; mt < 4; ++mt) {
        int r = wr * 64 + mt * 16 + (lane & 15);
        int c = kk * 64 + cbyte;
        af[kk][mt] = *(const f16x8*)(la + r * 128 + (c ^ ((r & 7) << 4)));
      }
#pragma unroll
      for (int nt = 0; nt < 4; ++nt) {
        int r = wc * 64 + nt * 16 + (lane & 15);
        int c = kk * 64 + cbyte;
        bfr[kk][nt] = *(const f16x8*)(lb + r * 128 + (c ^ ((r & 7) << 4)));
      }
    }
#pragma unroll
    for (int kk = 0; kk < 2; ++kk)
#pragma unroll
      for (int mt = 0; mt < 4; ++mt)
#pragma unroll
        for (int nt = 0; nt < 4; ++nt)
          acc[mt][nt] = __builtin_amdgcn_mfma_f32_16x16x32_f16(af[kk][mt], bfr[kk][nt], acc[mt][nt], 0, 0, 0);
    asm volatile("s_waitcnt vmcnt(0)" ::: "memory");
    __syncthreads();
  }
#undef STAGE

  int rb = 4 * (lane >> 4);
#pragma unroll
  for (int nt = 0; nt < 4; ++nt) {
    int col = n0 + wc * 64 + nt * 16 + (lane & 15);
    float bv = (MODE == 1) ? g.bias[col] : 0.0f;
#pragma unroll
    for (int mt = 0; mt < 4; ++mt) {
#pragma unroll
      for (int r = 0; r < 4; ++r) {
        int row = m0 + wr * 64 + mt * 16 + rb + r;
        size_t idx = (size_t)z * g.sCz + (size_t)row * g.ldc + col;
        float v = acc[mt][nt][r] + bv;
        if (MODE == 2) g.Cf[idx] = v; else g.Ch[idx] = (_Float16)v;
      }
    }
  }
}

// ---------------- row softmax: scores f32 (.,512) -> p f16 ----------------
__global__ __launch_bounds__(256) void softmax_rows(const float* __restrict__ sc, _Float16* __restrict__ p) {
  int row = blockIdx.x * 4 + (threadIdx.x >> 6);
  int lane = threadIdx.x & 63;
  const float* s = sc + (size_t)row * 512 + lane * 8;
  float v[8];
  float4 q0 = *(const float4*)s, q1 = *(const float4*)(s + 4);
  v[0]=q0.x; v[1]=q0.y; v[2]=q0.z; v[3]=q0.w; v[4]=q1.x; v[5]=q1.y; v[6]=q1.z; v[7]=q1.w;
  float mx = v[0];
#pragma unroll
  for (int j = 1; j < 8; ++j) mx = fmaxf(mx, v[j]);
  for (int o = 32; o; o >>= 1) mx = fmaxf(mx, __shfl_xor(mx, o));
  float sum = 0.f;
#pragma unroll
  for (int j = 0; j < 8; ++j) { v[j] = expf(v[j] - mx); sum += v[j]; }
  for (int o = 32; o; o >>= 1) sum += __shfl_xor(sum, o);
  float inv = 1.0f / sum;
  _Float16* pd = p + (size_t)row * 512 + lane * 8;
#pragma unroll
  for (int j = 0; j < 8; ++j) pd[j] = (_Float16)(v[j] * inv);
}

// ---------------- per-batch transpose: allhT[b][d][t] = allh[b][t][d] ----------------
__global__ void transpose_bt(const _Float16* __restrict__ allh, _Float16* __restrict__ allhT) {
  __shared__ _Float16 tile[32][33];
  int b = blockIdx.z;
  int d0 = blockIdx.x * 32, t0 = blockIdx.y * 32;
  int tx = threadIdx.x, ty = threadIdx.y;  // (32, 8)
  const _Float16* in = allh + (size_t)b * Tt * D2H;
  _Float16* outp = allhT + (size_t)b * D2H * Tt;
#pragma unroll
  for (int j = 0; j < 4; ++j)
    tile[ty + 8 * j][tx] = in[(size_t)(t0 + ty + 8 * j) * D2H + d0 + tx];
  __syncthreads();
#pragma unroll
  for (int j = 0; j < 4; ++j)
    outp[(size_t)(d0 + ty + 8 * j) * Tt + t0 + tx] = tile[tx][ty + 8 * j];
}

// ---------------- gating epilogue: attn = g*f + (1-g)*allh ----------------
__global__ __launch_bounds__(256) void gating(const _Float16* __restrict__ gfpre,
                                              const _Float16* __restrict__ allh,
                                              const float* __restrict__ bg,
                                              const float* __restrict__ bfv,
                                              float* __restrict__ out_attn) {
  int i = blockIdx.x * 256 + threadIdx.x;   // over (B*T) * 128 groups
  int m = i >> 7, c0 = (i & 127) << 3;
  f16x8 gv = *(const f16x8*)(gfpre + (size_t)m * 2048 + c0);
  f16x8 fv = *(const f16x8*)(gfpre + (size_t)m * 2048 + 1024 + c0);
  f16x8 ah = *(const f16x8*)(allh + (size_t)m * D2H + c0);
  float res[8];
#pragma unroll
  for (int j = 0; j < 8; ++j) {
    float gg = sigm((float)gv[j] + bg[c0 + j]);
    float ff = tanhf((float)fv[j] + bfv[c0 + j]);
    res[j] = gg * ff + (1.0f - gg) * (float)ah[j];
  }
  float4* dst = (float4*)(out_attn + (size_t)m * D2H + c0);
  dst[0] = make_float4(res[0], res[1], res[2], res[3]);
  dst[1] = make_float4(res[4], res[5], res[6], res[7]);
}

// ---------------- final concat output ----------------
__global__ void write_concat(const float* __restrict__ h1fin, float* __restrict__ out) {
  int i = blockIdx.x * 256 + threadIdx.x;
  if (i >= Bb * D2H) return;
  int b = i >> 10, c = i & 1023;
  out[i] = (c < Hh) ? h1fin[(size_t)b * Hh + c] : h1fin[(size_t)(Bb + b) * Hh + (c - Hh)];
}

// =============================== host ===============================
extern "C" void kernel_launch(void* const* d_in, const int* in_sizes, int n_in,
                              void* d_out, int out_size, void* d_ws, size_t ws_size,
                              hipStream_t stream) {
  const int*   context = (const int*)d_in[0];
  const int*   tags    = (const int*)d_in[1];
  const float* glove   = (const float*)d_in[2];
  const float* bio     = (const float*)d_in[3];
  const float* b_lin   = (const float*)d_in[21];
  const float* b_g     = (const float*)d_in[23];
  const float* b_f     = (const float*)d_in[25];

  char* ws = (char*)d_ws;
  size_t off = 0;
  auto carve = [&](size_t bytes) -> void* {
    void* pp = ws + off;
    off = (off + bytes + 255) & ~(size_t)255;
    return pp;
  };

  _Float16* xt = (_Float16*)carve((size_t)Tt * Bb * INPP * 2);
  _Float16 *Wx16[2][2], *Wh16[2][2];
  Wx16[0][0] = (_Float16*)carve((size_t)1536 * 320 * 2);
  Wx16[1][0] = (_Float16*)carve((size_t)1536 * 320 * 2);
  Wx16[0][1] = (_Float16*)carve((size_t)1536 * 512 * 2);
  Wx16[1][1] = (_Float16*)carve((size_t)1536 * 512 * 2);
  for (int d = 0; d < 2; ++d)
    for (int l = 0; l < 2; ++l) Wh16[d][l] = (_Float16*)carve((size_t)1536 * 512 * 2);
  _Float16* wlin = (_Float16*)carve((size_t)1024 * 1024 * 2);
  _Float16* wgf  = (_Float16*)carve((size_t)2048 * 2048 * 2);
  _Float16* allh  = (_Float16*)carve((size_t)Bb * Tt * D2H * 2);      // 64 MiB
  _Float16* allhT = (_Float16*)carve((size_t)Bb * Tt * D2H * 2);      // 64 MiB (hb / gf_pre alias)
  float*    scores = (float*)carve((size_t)Bb * Tt * Tt * 4);          // 64 MiB (hb / gf_pre alias)
  _Float16* pmat   = (_Float16*)carve((size_t)Bb * Tt * Tt * 2);       // 32 MiB (hb tail alias)
  _Float16* qctx   = (_Float16*)carve((size_t)Bb * Tt * D2H * 2);      // q, then ctx
  float*    h1fin  = (float*)carve((size_t)2 * Bb * Hh * 4);
  unsigned* flags  = (unsigned*)carve((size_t)4 * 32 * 16 * 4);        // 8KB

  // hb: (Tt+1)*4*SLAB*2 = 128.25 MiB, aliases allhT+scores+pmat-head (dead during recurrence)
  _Float16* hb = allhT;
  // gf_pre: 32768 x 2048 f16 = 128 MiB, aliases allhT+scores exactly (dead by gf time)
  _Float16* gfpre = allhT;

  hipMemsetAsync(hb, 0, (size_t)4 * SLAB * 2, stream);          // slab t=0 (4 units) = 0
  hipMemsetAsync(flags, 0, (size_t)4 * 32 * 16 * 4, stream);    // progress flags

  auto conv = [&](const void* src, _Float16* dst, int rows, int csrc, int cdst) {
    int total = rows * cdst;
    convert_pad<<<(total + 255) / 256, 256, 0, stream>>>((const float*)src, dst, rows, csrc, cdst);
  };
  conv(d_in[4],  Wx16[0][0], 1536, 303, 320);
  conv(d_in[12], Wx16[1][0], 1536, 303, 320);
  conv(d_in[8],  Wx16[0][1], 1536, 512, 512);
  conv(d_in[16], Wx16[1][1], 1536, 512, 512);
  conv(d_in[5],  Wh16[0][0], 1536, 512, 512);
  conv(d_in[13], Wh16[1][0], 1536, 512, 512);
  conv(d_in[9],  Wh16[0][1], 1536, 512, 512);
  conv(d_in[17], Wh16[1][1], 1536, 512, 512);
  conv(d_in[20], wlin, 1024, 1024, 1024);
  conv(d_in[22], wgf, 1024, 2048, 2048);
  conv(d_in[24], wgf + (size_t)1024 * 2048, 1024, 2048, 2048);

  embed_kernel<<<Tt * Bb, 64, 0, stream>>>(context, tags, glove, bio, xt);

  GruParams GP;
  GP.xt = xt;
  GP.Wx[0] = Wx16[0][0]; GP.Wx[1] = Wx16[1][0]; GP.Wx[2] = Wx16[0][1]; GP.Wx[3] = Wx16[1][1];
  GP.Wh[0] = Wh16[0][0]; GP.Wh[1] = Wh16[1][0]; GP.Wh[2] = Wh16[0][1]; GP.Wh[3] = Wh16[1][1];
  GP.bih[0] = (const float*)d_in[6];  GP.bhh[0] = (const float*)d_in[7];
  GP.bih[1] = (const float*)d_in[14]; GP.bhh[1] = (const float*)d_in[15];
  GP.bih[2] = (const float*)d_in[10]; GP.bhh[2] = (const float*)d_in[11];
  GP.bih[3] = (const float*)d_in[18]; GP.bhh[3] = (const float*)d_in[19];
  GP.hb = hb;
  GP.allh = allh;
  GP.h1fin = h1fin;

  gru_persist<<<128, 256, 0, stream>>>(GP, flags);

  TArgs ga;
  // q = all_h @ W_lin^T + b_lin -> f16 qctx
  ga.A = allh; ga.A2 = allh; ga.B = wlin;
  ga.Ch = qctx; ga.Cf = nullptr; ga.bias = b_lin;
  ga.lda = 1024; ga.ldb = 1024; ga.ldc = 1024; ga.K = 1024; ga.Ksplit = 1 << 30;
  ga.sAz = 0; ga.sBz = 0; ga.sCz = 0;
  gemm_tiled<1><<<dim3(8, 256, 1), 256, 0, stream>>>(ga);

  // scores[b] = q[b] @ all_h[b]^T -> f32
  ga.A = qctx; ga.A2 = qctx; ga.B = allh;
  ga.Ch = nullptr; ga.Cf = scores; ga.bias = nullptr;
  ga.lda = 1024; ga.ldb = 1024; ga.ldc = 512; ga.K = 1024; ga.Ksplit = 1 << 30;
  ga.sAz = (long long)512 * 1024; ga.sBz = (long long)512 * 1024; ga.sCz = (long long)512 * 512;
  gemm_tiled<2><<<dim3(4, 4, 64), 256, 0, stream>>>(ga);

  softmax_rows<<<(Bb * Tt) / 4, 256, 0, stream>>>(scores, pmat);

  transpose_bt<<<dim3(32, 16, 64), dim3(32, 8), 0, stream>>>(allh, allhT);

  // ctx[b] = p[b] @ (all_hT[b])^T -> f16 (overwrites q in qctx)
  ga.A = pmat; ga.A2 = pmat; ga.B = allhT;
  ga.Ch = qctx; ga.Cf = nullptr; ga.bias = nullptr;
  ga.lda = 512; ga.ldb = 512; ga.ldc = 1024; ga.K = 512; ga.Ksplit = 1 << 30;
  ga.sAz = (long long)512 * 512; ga.sBz = (long long)1024 * 512; ga.sCz = (long long)512 * 1024;
  gemm_tiled<0><<<dim3(8, 4, 64), 256, 0, stream>>>(ga);

  // gf_pre = [ctx | all_h] @ Wgf^T -> f16 (overwrites allhT+scores region)
  ga.A = qctx; ga.A2 = allh; ga.B = wgf;
  ga.Ch = gfpre; ga.Cf = nullptr; ga.bias = nullptr;
  ga.lda = 1024; ga.ldb = 2048; ga.ldc = 2048; ga.K = 2048; ga.Ksplit = 1024;
  ga.sAz = 0; ga.sBz = 0; ga.sCz = 0;
  gemm_tiled<0><<<dim3(16, 256, 1), 256, 0, stream>>>(ga);

  float* out_attn = (float*)d_out + (size_t)Bb * D2H;
  gating<<<(Bb * Tt * 128) / 256, 256, 0, stream>>>(gfpre, allh, b_g, b_f, out_attn);

  write_concat<<<(Bb * D2H + 255) / 256, 256, 0, stream>>>(h1fin, (float*)d_out);
}